// Round 1
// 313.002 us; speedup vs baseline: 1.0648x; 1.0648x over previous
//
#include <hip/hip_runtime.h>
#include <cstddef>
#include <cstdint>

// ---------------------------------------------------------------------------
// MAB fused block. B=4 N=M=2048 C=1024 H=16 d=64. bf16 MFMA internally.
// R7: attention rewritten — per-wave 32-q slice computes S^T over full 128 kv,
// so P stays in registers (no Ps LDS round-trip, no bank conflicts, 2 barriers
// per K-tile instead of 4). Enabled by a sigma-permuted V^T layout: within each
// 32-kv block, position p=[kg1 kg0 hi r1 r0] holds kv=[hi kg1 kg0 r1 r0], so a
// lane's own MFMA S-accumulator fragment IS the PV A-fragment (zero shuffles).
// gemm_qkv z=2 writes Vt in this layout (address change only, same 8B stores).
// LDS 49->32.5 KB (4 blocks/CU), setprio(1) around MFMA clusters (T5).
// ---------------------------------------------------------------------------

typedef unsigned short ushort_t;
typedef __attribute__((ext_vector_type(8))) short bf16x8;
typedef __attribute__((ext_vector_type(4))) float floatx4;
typedef __attribute__((ext_vector_type(8))) unsigned short us8;
typedef __attribute__((ext_vector_type(4))) unsigned short us4;

__device__ __forceinline__ ushort_t f2bf(float x) {   // RNE
  union { float f; unsigned u; } v; v.f = x;
  unsigned r = v.u + 0x7FFFu + ((v.u >> 16) & 1u);
  return (ushort_t)(r >> 16);
}
__device__ __forceinline__ float bf2f(ushort_t x) {
  union { unsigned u; float f; } v; v.u = ((unsigned)x) << 16;
  return v.f;
}
// pack two f32 -> [bf16(b):bf16(a)] via +0x8000 + v_perm (round-half-up)
__device__ __forceinline__ unsigned pk2(float a, float b) {
  union { float f; unsigned u; } x, y; x.f = a; y.f = b;
  return __builtin_amdgcn_perm(y.u + 0x8000u, x.u + 0x8000u, 0x07060302u);
}
__device__ __forceinline__ floatx4 mfma16(bf16x8 a, bf16x8 b, floatx4 c) {
  return __builtin_amdgcn_mfma_f32_16x16x32_bf16(a, b, c, 0, 0, 0);
}
__device__ __forceinline__ void gld_lds16(const void* g, void* l) {
  __builtin_amdgcn_global_load_lds(
      (const __attribute__((address_space(1))) unsigned int*)g,
      (__attribute__((address_space(3))) unsigned int*)l, 16, 0, 0);
}

// ---------------------------------------------------------------------------
// f32 -> bf16, 8 elems/thread, 4 tensors by blockIdx.z.
// ---------------------------------------------------------------------------
__global__ void cvt4(const float* __restrict__ i0, const float* __restrict__ i1,
                     const float* __restrict__ i2, const float* __restrict__ i3,
                     ushort_t* __restrict__ o0, ushort_t* __restrict__ o1,
                     ushort_t* __restrict__ o2, ushort_t* __restrict__ o3, int n8) {
  int z = blockIdx.z;
  const float* in = z == 0 ? i0 : z == 1 ? i1 : z == 2 ? i2 : i3;
  ushort_t* out = z == 0 ? o0 : z == 1 ? o1 : z == 2 ? o2 : o3;
  int i = blockIdx.x * 256 + threadIdx.x;
  if (i < n8) {
    const float4* p = (const float4*)in + (size_t)i * 2;
    float4 a = p[0], b = p[1];
    uint4 o;
    o.x = pk2(a.x, a.y); o.y = pk2(a.z, a.w);
    o.z = pk2(b.x, b.y); o.w = pk2(b.z, b.w);
    *((uint4*)out + i) = o;
  }
}

// ---------------------------------------------------------------------------
// Fused QKV projections. z=0: Qp; z=1: Kp; z=2: Vt (bf16, transposed
// [1024 dv][8192 kv], sigma-permuted within each 32-kv block).
// 128x128 tile, BK=64, 3-bit XOR chunk swizzle.
// ---------------------------------------------------------------------------
__global__ __launch_bounds__(256, 2)
void gemm_qkv(const ushort_t* __restrict__ Qb, const ushort_t* __restrict__ Kb,
              const ushort_t* __restrict__ Wqb, const ushort_t* __restrict__ Wkb,
              const ushort_t* __restrict__ Wvb,
              const float* __restrict__ bq, const float* __restrict__ bk,
              const float* __restrict__ bv,
              ushort_t* __restrict__ Qp, ushort_t* __restrict__ Kp,
              ushort_t* __restrict__ Vt)
{
  const int Kd = 1024, Nn = 1024;
  const int z = blockIdx.z;
  const ushort_t* Ab = (z == 0) ? Qb : Kb;
  const ushort_t* Bw = (z == 0) ? Wqb : (z == 1) ? Wkb : Wvb;
  const float* bias  = (z == 0) ? bq : (z == 1) ? bk : bv;

  __shared__ __align__(16) ushort_t As[128][64];
  __shared__ __align__(16) ushort_t Bs[128][64];
  const int tid = threadIdx.x;
  const int lane = tid & 63, wave = tid >> 6;
  const int wm = (wave >> 1) * 64, wn = (wave & 1) * 64;
  const int rq = lane & 15, kg = lane >> 4;
  const int row0 = blockIdx.y * 128, col0 = blockIdx.x * 128;

  const int st_sub = lane >> 3;                 // row within 8-row group
  const int st_cs  = (lane & 7) ^ st_sub;       // swizzled source 16B chunk

  floatx4 acc[4][4];
#pragma unroll
  for (int i = 0; i < 4; ++i)
#pragma unroll
    for (int j = 0; j < 4; ++j) acc[i][j] = (floatx4){0.f, 0.f, 0.f, 0.f};

  for (int k0 = 0; k0 < Kd; k0 += 64) {
    __syncthreads();
#pragma unroll
    for (int r = 0; r < 4; ++r) {
      int i = wave * 4 + r;                     // 0..15, 8 rows each
      int row = i * 8 + st_sub;
      gld_lds16(Ab + (size_t)(row0 + row) * Kd + k0 + st_cs * 8, (ushort_t*)As + i * 512);
      gld_lds16(Bw + (size_t)(col0 + row) * Kd + k0 + st_cs * 8, (ushort_t*)Bs + i * 512);
    }
    __syncthreads();
#pragma unroll
    for (int kq = 0; kq < 2; ++kq) {
      bf16x8 af[4], bfr[4];
#pragma unroll
      for (int mi = 0; mi < 4; ++mi)
        af[mi] = *(const bf16x8*)&As[wm + mi*16 + rq][((kq*4 + kg) ^ (rq & 7)) * 8];
#pragma unroll
      for (int ni = 0; ni < 4; ++ni)
        bfr[ni] = *(const bf16x8*)&Bs[wn + ni*16 + rq][((kq*4 + kg) ^ (rq & 7)) * 8];
#pragma unroll
      for (int mi = 0; mi < 4; ++mi)
#pragma unroll
        for (int ni = 0; ni < 4; ++ni)
          acc[mi][ni] = mfma16(af[mi], bfr[ni], acc[mi][ni]);
    }
  }

  float bv4[4];
#pragma unroll
  for (int ni = 0; ni < 4; ++ni) bv4[ni] = bias[col0 + wn + ni*16 + rq];

  if (z < 2) {
    ushort_t* Cb = (z == 0) ? Qp : Kp;
#pragma unroll
    for (int mi = 0; mi < 4; ++mi)
#pragma unroll
      for (int ni = 0; ni < 4; ++ni)
#pragma unroll
        for (int rr = 0; rr < 4; ++rr) {
          int row = row0 + wm + mi*16 + kg*4 + rr;
          int col = col0 + wn + ni*16 + rq;
          Cb[(size_t)row * Nn + col] = f2bf(acc[mi][ni][rr] + bv4[ni]);
        }
  } else {
    // sigma layout: kv = base32 + [hi kg1 kg0 r1 r0] stored at
    // position base32 + [kg1 kg0 hi r1 r0]  (hi = mi&1)
#pragma unroll
    for (int mi = 0; mi < 4; ++mi)
#pragma unroll
      for (int ni = 0; ni < 4; ++ni) {
        int col = col0 + wn + ni*16 + rq;       // dv
        int base32 = row0 + wm + (mi >> 1) * 32;
        int p = kg * 8 + (mi & 1) * 4;          // r 0..3 contiguous
        us4 o = { f2bf(acc[mi][ni][0] + bv4[ni]), f2bf(acc[mi][ni][1] + bv4[ni]),
                  f2bf(acc[mi][ni][2] + bv4[ni]), f2bf(acc[mi][ni][3] + bv4[ni]) };
        *(us4*)(Vt + (size_t)col * 8192 + base32 + p) = o;
      }
  }
}

// ---------------------------------------------------------------------------
// Output GEMM: out = bf2f(Ob) + relu(Ob*Wo^T + bo), f32 out. BK=64.
// ---------------------------------------------------------------------------
__global__ __launch_bounds__(256, 2)
void gemm_out(const ushort_t* __restrict__ Ob, const ushort_t* __restrict__ Bw,
              const float* __restrict__ bias, float* __restrict__ Out)
{
  const int Kd = 1024, Nn = 1024;
  __shared__ __align__(16) ushort_t As[128][64];
  __shared__ __align__(16) ushort_t Bs[128][64];
  const int tid = threadIdx.x;
  const int lane = tid & 63, wave = tid >> 6;
  const int wm = (wave >> 1) * 64, wn = (wave & 1) * 64;
  const int rq = lane & 15, kg = lane >> 4;
  const int row0 = blockIdx.y * 128, col0 = blockIdx.x * 128;

  const int st_sub = lane >> 3;
  const int st_cs  = (lane & 7) ^ st_sub;

  floatx4 acc[4][4];
#pragma unroll
  for (int i = 0; i < 4; ++i)
#pragma unroll
    for (int j = 0; j < 4; ++j) acc[i][j] = (floatx4){0.f, 0.f, 0.f, 0.f};

  for (int k0 = 0; k0 < Kd; k0 += 64) {
    __syncthreads();
#pragma unroll
    for (int r = 0; r < 4; ++r) {
      int i = wave * 4 + r;
      int row = i * 8 + st_sub;
      gld_lds16(Ob + (size_t)(row0 + row) * Kd + k0 + st_cs * 8, (ushort_t*)As + i * 512);
      gld_lds16(Bw + (size_t)(col0 + row) * Kd + k0 + st_cs * 8, (ushort_t*)Bs + i * 512);
    }
    __syncthreads();
#pragma unroll
    for (int kq = 0; kq < 2; ++kq) {
      bf16x8 af[4], bfr[4];
#pragma unroll
      for (int mi = 0; mi < 4; ++mi)
        af[mi] = *(const bf16x8*)&As[wm + mi*16 + rq][((kq*4 + kg) ^ (rq & 7)) * 8];
#pragma unroll
      for (int ni = 0; ni < 4; ++ni)
        bfr[ni] = *(const bf16x8*)&Bs[wn + ni*16 + rq][((kq*4 + kg) ^ (rq & 7)) * 8];
#pragma unroll
      for (int mi = 0; mi < 4; ++mi)
#pragma unroll
        for (int ni = 0; ni < 4; ++ni)
          acc[mi][ni] = mfma16(af[mi], bfr[ni], acc[mi][ni]);
    }
  }

  float bv4[4];
#pragma unroll
  for (int ni = 0; ni < 4; ++ni) bv4[ni] = bias[col0 + wn + ni*16 + rq];
#pragma unroll
  for (int mi = 0; mi < 4; ++mi)
#pragma unroll
    for (int ni = 0; ni < 4; ++ni)
#pragma unroll
      for (int rr = 0; rr < 4; ++rr) {
        int row = row0 + wm + mi*16 + kg*4 + rr;
        int col = col0 + wn + ni*16 + rq;
        size_t idx = (size_t)row * Nn + col;
        float pre = acc[mi][ni][rr] + bv4[ni];
        Out[idx] = bf2f(Ob[idx]) + (pre > 0.f ? pre : 0.f);
      }
}

// ---------------------------------------------------------------------------
// Flash attention (no-max softmax). BQ=128, BKV=128, d=64, all bf16.
// Wave w owns q rows [w*32, w*32+32); computes S^T = K*Q^T over the FULL
// 128-kv tile, softmax + P-pack entirely in registers, then PV with P as the
// in-register A-operand (sigma-layout V^T makes the fragment line up).
// LDS: Ks 16 KB + Vs 16 KB + reds 512 B = 32.5 KB -> 4 blocks/CU.
// 2 barriers per K-tile.
// ---------------------------------------------------------------------------
__global__ __launch_bounds__(256, 2)
void attn_kernel(const ushort_t* __restrict__ Qp,
                 const ushort_t* __restrict__ Kp,
                 const ushort_t* __restrict__ Vt,
                 ushort_t* __restrict__ Ob)
{
  const float sc2 = 0.045084439f;  // (1/32) * log2(e)
  const int qt = blockIdx.x;       // 0..15
  const int bh = blockIdx.y;       // 0..63
  const int b = bh >> 4, h = bh & 15;
  const int q0 = qt * 128;

  __shared__ __align__(16) ushort_t Ks[8192];   // K[128][64] (also Q staging)
  __shared__ __align__(16) ushort_t Vs[8192];   // V^T[64][128], sigma kv layout
  __shared__ float reds[128];

  const int tid = threadIdx.x, lane = tid & 63, wq = tid >> 6;  // wq: q-quarter
  const int rq = lane & 15, kg = lane >> 4;

  const size_t qkbase = (size_t)(b * 2048) * 1024 + h * 64;

  // stage Q tile (128x64) into Ks, 3-bit chunk swizzle
#pragma unroll
  for (int r = 0; r < 4; ++r) {
    int i = wq * 4 + r;
    int row = i * 8 + (lane >> 3);
    int cs = (lane & 7) ^ (lane >> 3);
    gld_lds16(Qp + qkbase + (size_t)(q0 + row) * 1024 + cs * 8, Ks + i * 512);
  }
  __syncthreads();

  // preload Q B-frags scaled by sc2: aq[ni][kq], q = wq*32 + ni*16 + rq
  bf16x8 aq[2][2];
#pragma unroll
  for (int ni = 0; ni < 2; ++ni)
#pragma unroll
    for (int kq = 0; kq < 2; ++kq) {
      int row = wq * 32 + ni * 16 + rq;
      int ch = (kq * 4 + kg) ^ (rq & 7);
      bf16x8 t = *(const bf16x8*)&Ks[row * 64 + ch * 8];
#pragma unroll
      for (int e = 0; e < 8; ++e)
        t[e] = (short)f2bf(bf2f((ushort_t)t[e]) * sc2);
      aq[ni][kq] = t;
    }

  floatx4 oacc[2][4];
  float l_st[2] = {0.f, 0.f};
#pragma unroll
  for (int nb = 0; nb < 2; ++nb)
#pragma unroll
    for (int dvb = 0; dvb < 4; ++dvb) oacc[nb][dvb] = (floatx4){0.f,0.f,0.f,0.f};

  for (int kt = 0; kt < 16; ++kt) {
    const int kv0 = kt * 128;
    __syncthreads();   // prev iter done reading Ks (S) and Vs (PV); aq read done
    // stage K (128 kv x 64 d) into Ks and V^T (64 dv x 128 kv-pos) into Vs
#pragma unroll
    for (int r = 0; r < 4; ++r) {
      int i = wq * 4 + r;
      int rowk = i * 8 + (lane >> 3);
      int csk = (lane & 7) ^ (lane >> 3);
      gld_lds16(Kp + qkbase + (size_t)(kv0 + rowk) * 1024 + csk * 8, Ks + i * 512);
      int dv = i * 4 + (lane >> 4);
      int csv = (lane & 15) ^ (dv & 7);
      gld_lds16(Vt + (size_t)(h * 64 + dv) * 8192 + b * 2048 + kv0 + csv * 8,
                Vs + i * 512);
    }
    __syncthreads();   // K + V landed

    // S^T = K * Q^T  (mi = kv block 0..7, ni = q block 0..1)
    floatx4 s[8][2];
#pragma unroll
    for (int mi = 0; mi < 8; ++mi) {
      s[mi][0] = (floatx4){0.f,0.f,0.f,0.f};
      s[mi][1] = (floatx4){0.f,0.f,0.f,0.f};
    }
    __builtin_amdgcn_s_setprio(1);
#pragma unroll
    for (int kq = 0; kq < 2; ++kq) {
      bf16x8 ak[8];
#pragma unroll
      for (int mi = 0; mi < 8; ++mi)
        ak[mi] = *(const bf16x8*)&Ks[(mi * 16 + rq) * 64 + (((kq * 4 + kg) ^ (rq & 7)) * 8)];
#pragma unroll
      for (int mi = 0; mi < 8; ++mi)
#pragma unroll
        for (int ni = 0; ni < 2; ++ni)
          s[mi][ni] = mfma16(ak[mi], aq[ni][kq], s[mi][ni]);
    }
    __builtin_amdgcn_s_setprio(0);

    // p = 2^s ; per-lane partial row sums (registers only)
#pragma unroll
    for (int mi = 0; mi < 8; ++mi)
#pragma unroll
      for (int ni = 0; ni < 2; ++ni)
#pragma unroll
        for (int rr = 0; rr < 4; ++rr)
          s[mi][ni][rr] = __builtin_amdgcn_exp2f(s[mi][ni][rr]);
#pragma unroll
    for (int ni = 0; ni < 2; ++ni) {
      float t = 0.f;
#pragma unroll
      for (int mi = 0; mi < 8; ++mi)
        t += (s[mi][ni][0] + s[mi][ni][1]) + (s[mi][ni][2] + s[mi][ni][3]);
      l_st[ni] += t;
    }

    // O += P V : P packed from own s regs (sigma layout), V^T from LDS
    __builtin_amdgcn_s_setprio(1);
#pragma unroll
    for (int c = 0; c < 4; ++c) {
      bf16x8 vf[4];
#pragma unroll
      for (int dvb = 0; dvb < 4; ++dvb) {
        int dv = dvb * 16 + rq;
        int ch = (c * 4 + kg) ^ (rq & 7);
        vf[dvb] = *(const bf16x8*)&Vs[dv * 128 + ch * 8];
      }
#pragma unroll
      for (int nb = 0; nb < 2; ++nb) {
        union { unsigned u[4]; bf16x8 v; } pa;
        pa.u[0] = pk2(s[2*c  ][nb][0], s[2*c  ][nb][1]);
        pa.u[1] = pk2(s[2*c  ][nb][2], s[2*c  ][nb][3]);
        pa.u[2] = pk2(s[2*c+1][nb][0], s[2*c+1][nb][1]);
        pa.u[3] = pk2(s[2*c+1][nb][2], s[2*c+1][nb][3]);
#pragma unroll
        for (int dvb = 0; dvb < 4; ++dvb)
          oacc[nb][dvb] = mfma16(pa.v, vf[dvb], oacc[nb][dvb]);
      }
    }
    __builtin_amdgcn_s_setprio(0);
  }

  // combine l across kg groups (each wave self-contained in q)
#pragma unroll
  for (int ni = 0; ni < 2; ++ni) {
    l_st[ni] += __shfl_xor(l_st[ni], 16, 64);
    l_st[ni] += __shfl_xor(l_st[ni], 32, 64);
  }
  if (lane < 16) {
    reds[wq * 32 + rq]      = l_st[0];
    reds[wq * 32 + 16 + rq] = l_st[1];
  }
  __syncthreads();

  // epilogue: Oh = Qh + O/l
#pragma unroll
  for (int nb = 0; nb < 2; ++nb)
#pragma unroll
    for (int rr = 0; rr < 4; ++rr) {
      int row = wq * 32 + nb * 16 + kg * 4 + rr;
      float linv = 1.0f / reds[row];
#pragma unroll
      for (int dvb = 0; dvb < 4; ++dvb) {
        int col = dvb * 16 + rq;
        size_t idx = qkbase + (size_t)(q0 + row) * 1024 + col;
        Ob[idx] = f2bf(oacc[nb][dvb][rr] * linv + bf2f(Qp[idx]));
      }
    }
}

// ---------------------------------------------------------------------------
extern "C" void kernel_launch(void* const* d_in, const int* in_sizes, int n_in,
                              void* d_out, int out_size, void* d_ws, size_t ws_size,
                              hipStream_t stream)
{
  const float* Q  = (const float*)d_in[0];
  const float* K  = (const float*)d_in[1];
  const float* Wq = (const float*)d_in[2];
  const float* bq = (const float*)d_in[3];
  const float* Wk = (const float*)d_in[4];
  const float* bk = (const float*)d_in[5];
  const float* Wv = (const float*)d_in[6];
  const float* bv = (const float*)d_in[7];
  const float* Wo = (const float*)d_in[8];
  const float* bo = (const float*)d_in[9];
  float* Out = (float*)d_out;

  ushort_t* ws = (ushort_t*)d_ws;
  const size_t E = (size_t)8192 * 1024;
  const size_t WSZ = (size_t)1024 * 1024;
  ushort_t* Qb  = ws;            // aliased by Ob after attention
  ushort_t* Kb  = ws + E;
  ushort_t* Qp  = ws + 2*E;
  ushort_t* Kp  = ws + 3*E;
  ushort_t* Vt  = ws + 4*E;      // bf16 V^T [1024][8192], sigma kv layout
  ushort_t* Wqb = ws + 5*E;
  ushort_t* Wkb = ws + 5*E + WSZ;
  ushort_t* Wvb = ws + 5*E + 2*WSZ;
  ushort_t* Wob = ws + 5*E + 3*WSZ;
  ushort_t* Ob  = Qb;

  cvt4<<<dim3(4096, 1, 2), 256, 0, stream>>>(Q, K, K, K, Qb, Kb, Kb, Kb, 1048576);
  cvt4<<<dim3(512, 1, 4), 256, 0, stream>>>(Wq, Wk, Wv, Wo, Wqb, Wkb, Wvb, Wob, 131072);

  dim3 blk(256);
  gemm_qkv<<<dim3(8, 64, 3), blk, 0, stream>>>(Qb, Kb, Wqb, Wkb, Wvb,
                                               bq, bk, bv, Qp, Kp, Vt);
  attn_kernel<<<dim3(16, 64), blk, 0, stream>>>(Qp, Kp, Vt, Ob);
  gemm_out<<<dim3(8, 64), blk, 0, stream>>>(Ob, Wob, bo, Out);
}

// Round 2
// 308.900 us; speedup vs baseline: 1.0790x; 1.0133x over previous
//
#include <hip/hip_runtime.h>
#include <cstddef>
#include <cstdint>

// ---------------------------------------------------------------------------
// MAB fused block. B=4 N=M=2048 C=1024 H=16 d=64. bf16 MFMA internally.
// R8: attention K/V staging double-buffered (T3-minimum 2-phase): per K-tile,
// issue STAGE(next -> buf^1) BEFORE compute(buf), single __syncthreads() per
// tile (its implicit vmcnt(0)/lgkmcnt(0) drain makes the 1-barrier schedule
// race-free). Stage latency hides under the 64-MFMA + softmax compute phase.
// LDS 32.5 -> 64.5 KB (2 blocks/CU; measured residency was ~2 anyway).
// P stays in registers via the sigma-permuted V^T layout (R7).
// ---------------------------------------------------------------------------

typedef unsigned short ushort_t;
typedef __attribute__((ext_vector_type(8))) short bf16x8;
typedef __attribute__((ext_vector_type(4))) float floatx4;
typedef __attribute__((ext_vector_type(8))) unsigned short us8;
typedef __attribute__((ext_vector_type(4))) unsigned short us4;

__device__ __forceinline__ ushort_t f2bf(float x) {   // RNE
  union { float f; unsigned u; } v; v.f = x;
  unsigned r = v.u + 0x7FFFu + ((v.u >> 16) & 1u);
  return (ushort_t)(r >> 16);
}
__device__ __forceinline__ float bf2f(ushort_t x) {
  union { unsigned u; float f; } v; v.u = ((unsigned)x) << 16;
  return v.f;
}
// pack two f32 -> [bf16(b):bf16(a)] via +0x8000 + v_perm (round-half-up)
__device__ __forceinline__ unsigned pk2(float a, float b) {
  union { float f; unsigned u; } x, y; x.f = a; y.f = b;
  return __builtin_amdgcn_perm(y.u + 0x8000u, x.u + 0x8000u, 0x07060302u);
}
__device__ __forceinline__ floatx4 mfma16(bf16x8 a, bf16x8 b, floatx4 c) {
  return __builtin_amdgcn_mfma_f32_16x16x32_bf16(a, b, c, 0, 0, 0);
}
__device__ __forceinline__ void gld_lds16(const void* g, void* l) {
  __builtin_amdgcn_global_load_lds(
      (const __attribute__((address_space(1))) unsigned int*)g,
      (__attribute__((address_space(3))) unsigned int*)l, 16, 0, 0);
}

// ---------------------------------------------------------------------------
// f32 -> bf16, 8 elems/thread, 4 tensors by blockIdx.z.
// ---------------------------------------------------------------------------
__global__ void cvt4(const float* __restrict__ i0, const float* __restrict__ i1,
                     const float* __restrict__ i2, const float* __restrict__ i3,
                     ushort_t* __restrict__ o0, ushort_t* __restrict__ o1,
                     ushort_t* __restrict__ o2, ushort_t* __restrict__ o3, int n8) {
  int z = blockIdx.z;
  const float* in = z == 0 ? i0 : z == 1 ? i1 : z == 2 ? i2 : i3;
  ushort_t* out = z == 0 ? o0 : z == 1 ? o1 : z == 2 ? o2 : o3;
  int i = blockIdx.x * 256 + threadIdx.x;
  if (i < n8) {
    const float4* p = (const float4*)in + (size_t)i * 2;
    float4 a = p[0], b = p[1];
    uint4 o;
    o.x = pk2(a.x, a.y); o.y = pk2(a.z, a.w);
    o.z = pk2(b.x, b.y); o.w = pk2(b.z, b.w);
    *((uint4*)out + i) = o;
  }
}

// ---------------------------------------------------------------------------
// Fused QKV projections. z=0: Qp; z=1: Kp; z=2: Vt (bf16, transposed
// [1024 dv][8192 kv], sigma-permuted within each 32-kv block).
// 128x128 tile, BK=64, 3-bit XOR chunk swizzle.
// ---------------------------------------------------------------------------
__global__ __launch_bounds__(256, 2)
void gemm_qkv(const ushort_t* __restrict__ Qb, const ushort_t* __restrict__ Kb,
              const ushort_t* __restrict__ Wqb, const ushort_t* __restrict__ Wkb,
              const ushort_t* __restrict__ Wvb,
              const float* __restrict__ bq, const float* __restrict__ bk,
              const float* __restrict__ bv,
              ushort_t* __restrict__ Qp, ushort_t* __restrict__ Kp,
              ushort_t* __restrict__ Vt)
{
  const int Kd = 1024, Nn = 1024;
  const int z = blockIdx.z;
  const ushort_t* Ab = (z == 0) ? Qb : Kb;
  const ushort_t* Bw = (z == 0) ? Wqb : (z == 1) ? Wkb : Wvb;
  const float* bias  = (z == 0) ? bq : (z == 1) ? bk : bv;

  __shared__ __align__(16) ushort_t As[128][64];
  __shared__ __align__(16) ushort_t Bs[128][64];
  const int tid = threadIdx.x;
  const int lane = tid & 63, wave = tid >> 6;
  const int wm = (wave >> 1) * 64, wn = (wave & 1) * 64;
  const int rq = lane & 15, kg = lane >> 4;
  const int row0 = blockIdx.y * 128, col0 = blockIdx.x * 128;

  const int st_sub = lane >> 3;                 // row within 8-row group
  const int st_cs  = (lane & 7) ^ st_sub;       // swizzled source 16B chunk

  floatx4 acc[4][4];
#pragma unroll
  for (int i = 0; i < 4; ++i)
#pragma unroll
    for (int j = 0; j < 4; ++j) acc[i][j] = (floatx4){0.f, 0.f, 0.f, 0.f};

  for (int k0 = 0; k0 < Kd; k0 += 64) {
    __syncthreads();
#pragma unroll
    for (int r = 0; r < 4; ++r) {
      int i = wave * 4 + r;                     // 0..15, 8 rows each
      int row = i * 8 + st_sub;
      gld_lds16(Ab + (size_t)(row0 + row) * Kd + k0 + st_cs * 8, (ushort_t*)As + i * 512);
      gld_lds16(Bw + (size_t)(col0 + row) * Kd + k0 + st_cs * 8, (ushort_t*)Bs + i * 512);
    }
    __syncthreads();
#pragma unroll
    for (int kq = 0; kq < 2; ++kq) {
      bf16x8 af[4], bfr[4];
#pragma unroll
      for (int mi = 0; mi < 4; ++mi)
        af[mi] = *(const bf16x8*)&As[wm + mi*16 + rq][((kq*4 + kg) ^ (rq & 7)) * 8];
#pragma unroll
      for (int ni = 0; ni < 4; ++ni)
        bfr[ni] = *(const bf16x8*)&Bs[wn + ni*16 + rq][((kq*4 + kg) ^ (rq & 7)) * 8];
#pragma unroll
      for (int mi = 0; mi < 4; ++mi)
#pragma unroll
        for (int ni = 0; ni < 4; ++ni)
          acc[mi][ni] = mfma16(af[mi], bfr[ni], acc[mi][ni]);
    }
  }

  float bv4[4];
#pragma unroll
  for (int ni = 0; ni < 4; ++ni) bv4[ni] = bias[col0 + wn + ni*16 + rq];

  if (z < 2) {
    ushort_t* Cb = (z == 0) ? Qp : Kp;
#pragma unroll
    for (int mi = 0; mi < 4; ++mi)
#pragma unroll
      for (int ni = 0; ni < 4; ++ni)
#pragma unroll
        for (int rr = 0; rr < 4; ++rr) {
          int row = row0 + wm + mi*16 + kg*4 + rr;
          int col = col0 + wn + ni*16 + rq;
          Cb[(size_t)row * Nn + col] = f2bf(acc[mi][ni][rr] + bv4[ni]);
        }
  } else {
    // sigma layout: kv = base32 + [hi kg1 kg0 r1 r0] stored at
    // position base32 + [kg1 kg0 hi r1 r0]  (hi = mi&1)
#pragma unroll
    for (int mi = 0; mi < 4; ++mi)
#pragma unroll
      for (int ni = 0; ni < 4; ++ni) {
        int col = col0 + wn + ni*16 + rq;       // dv
        int base32 = row0 + wm + (mi >> 1) * 32;
        int p = kg * 8 + (mi & 1) * 4;          // r 0..3 contiguous
        us4 o = { f2bf(acc[mi][ni][0] + bv4[ni]), f2bf(acc[mi][ni][1] + bv4[ni]),
                  f2bf(acc[mi][ni][2] + bv4[ni]), f2bf(acc[mi][ni][3] + bv4[ni]) };
        *(us4*)(Vt + (size_t)col * 8192 + base32 + p) = o;
      }
  }
}

// ---------------------------------------------------------------------------
// Output GEMM: out = bf2f(Ob) + relu(Ob*Wo^T + bo), f32 out. BK=64.
// ---------------------------------------------------------------------------
__global__ __launch_bounds__(256, 2)
void gemm_out(const ushort_t* __restrict__ Ob, const ushort_t* __restrict__ Bw,
              const float* __restrict__ bias, float* __restrict__ Out)
{
  const int Kd = 1024, Nn = 1024;
  __shared__ __align__(16) ushort_t As[128][64];
  __shared__ __align__(16) ushort_t Bs[128][64];
  const int tid = threadIdx.x;
  const int lane = tid & 63, wave = tid >> 6;
  const int wm = (wave >> 1) * 64, wn = (wave & 1) * 64;
  const int rq = lane & 15, kg = lane >> 4;
  const int row0 = blockIdx.y * 128, col0 = blockIdx.x * 128;

  const int st_sub = lane >> 3;
  const int st_cs  = (lane & 7) ^ st_sub;

  floatx4 acc[4][4];
#pragma unroll
  for (int i = 0; i < 4; ++i)
#pragma unroll
    for (int j = 0; j < 4; ++j) acc[i][j] = (floatx4){0.f, 0.f, 0.f, 0.f};

  for (int k0 = 0; k0 < Kd; k0 += 64) {
    __syncthreads();
#pragma unroll
    for (int r = 0; r < 4; ++r) {
      int i = wave * 4 + r;
      int row = i * 8 + st_sub;
      gld_lds16(Ob + (size_t)(row0 + row) * Kd + k0 + st_cs * 8, (ushort_t*)As + i * 512);
      gld_lds16(Bw + (size_t)(col0 + row) * Kd + k0 + st_cs * 8, (ushort_t*)Bs + i * 512);
    }
    __syncthreads();
#pragma unroll
    for (int kq = 0; kq < 2; ++kq) {
      bf16x8 af[4], bfr[4];
#pragma unroll
      for (int mi = 0; mi < 4; ++mi)
        af[mi] = *(const bf16x8*)&As[wm + mi*16 + rq][((kq*4 + kg) ^ (rq & 7)) * 8];
#pragma unroll
      for (int ni = 0; ni < 4; ++ni)
        bfr[ni] = *(const bf16x8*)&Bs[wn + ni*16 + rq][((kq*4 + kg) ^ (rq & 7)) * 8];
#pragma unroll
      for (int mi = 0; mi < 4; ++mi)
#pragma unroll
        for (int ni = 0; ni < 4; ++ni)
          acc[mi][ni] = mfma16(af[mi], bfr[ni], acc[mi][ni]);
    }
  }

  float bv4[4];
#pragma unroll
  for (int ni = 0; ni < 4; ++ni) bv4[ni] = bias[col0 + wn + ni*16 + rq];
#pragma unroll
  for (int mi = 0; mi < 4; ++mi)
#pragma unroll
    for (int ni = 0; ni < 4; ++ni)
#pragma unroll
      for (int rr = 0; rr < 4; ++rr) {
        int row = row0 + wm + mi*16 + kg*4 + rr;
        int col = col0 + wn + ni*16 + rq;
        size_t idx = (size_t)row * Nn + col;
        float pre = acc[mi][ni][rr] + bv4[ni];
        Out[idx] = bf2f(Ob[idx]) + (pre > 0.f ? pre : 0.f);
      }
}

// ---------------------------------------------------------------------------
// Flash attention (no-max softmax). BQ=128, BKV=128, d=64, all bf16.
// Wave w owns q rows [w*32, w*32+32); computes S^T = K*Q^T over the FULL
// 128-kv tile, softmax + P-pack entirely in registers, then PV with P as the
// in-register A-operand (sigma-layout V^T makes the fragment line up).
// R8: double-buffered K/V staging, ONE barrier per K-tile (T3-minimum):
//   loop { STAGE(t+1 -> buf^1); compute(buf); __syncthreads(); swap; }
// The barrier's implicit vmcnt(0)/lgkmcnt(0) drain proves: next tile landed,
// and every wave finished reading buf -> next iteration may overwrite it.
// LDS: 2x(Ks 16K + Vs 16K) + reds 512 B = 64.5 KB -> 2 blocks/CU.
// ---------------------------------------------------------------------------
__global__ __launch_bounds__(256, 2)
void attn_kernel(const ushort_t* __restrict__ Qp,
                 const ushort_t* __restrict__ Kp,
                 const ushort_t* __restrict__ Vt,
                 ushort_t* __restrict__ Ob)
{
  const float sc2 = 0.045084439f;  // (1/32) * log2(e)
  const int qt = blockIdx.x;       // 0..15
  const int bh = blockIdx.y;       // 0..63
  const int b = bh >> 4, h = bh & 15;
  const int q0 = qt * 128;

  __shared__ __align__(16) ushort_t Ks[2][8192];  // K[128][64] per buf
  __shared__ __align__(16) ushort_t Vs[2][8192];  // V^T[64][128] sigma, per buf
  __shared__ float reds[128];

  const int tid = threadIdx.x, lane = tid & 63, wq = tid >> 6;  // wq: q-quarter
  const int rq = lane & 15, kg = lane >> 4;

  const size_t qkbase = (size_t)(b * 2048) * 1024 + h * 64;

  // per-lane staging geometry (shared by Q/K and V paths)
  const int sg_sub = lane >> 3;               // row within 8-row group
  const int sg_csk = (lane & 7) ^ sg_sub;     // swizzled 16B chunk (64-col row)

  // stage Q tile (128x64) into Ks[1]
#pragma unroll
  for (int r = 0; r < 4; ++r) {
    int i = wq * 4 + r;
    int row = i * 8 + sg_sub;
    gld_lds16(Qp + qkbase + (size_t)(q0 + row) * 1024 + sg_csk * 8, &Ks[1][i * 512]);
  }
  __syncthreads();

  // issue tile-0 K/V stage into buf 0 (overlaps with aq extraction below)
  auto stage = [&](int kt, int bufi) {
    const int kv0 = kt * 128;
#pragma unroll
    for (int r = 0; r < 4; ++r) {
      int i = wq * 4 + r;
      int rowk = i * 8 + sg_sub;
      gld_lds16(Kp + qkbase + (size_t)(kv0 + rowk) * 1024 + sg_csk * 8,
                &Ks[bufi][i * 512]);
      int dv = i * 4 + (lane >> 4);
      int csv = (lane & 15) ^ (dv & 7);
      gld_lds16(Vt + (size_t)(h * 64 + dv) * 8192 + b * 2048 + kv0 + csv * 8,
                &Vs[bufi][i * 512]);
    }
  };
  stage(0, 0);

  // preload Q B-frags scaled by sc2 from Ks[1]: aq[ni][kq], q = wq*32+ni*16+rq
  bf16x8 aq[2][2];
#pragma unroll
  for (int ni = 0; ni < 2; ++ni)
#pragma unroll
    for (int kq = 0; kq < 2; ++kq) {
      int row = wq * 32 + ni * 16 + rq;
      int ch = (kq * 4 + kg) ^ (rq & 7);
      bf16x8 t = *(const bf16x8*)&Ks[1][row * 64 + ch * 8];
#pragma unroll
      for (int e = 0; e < 8; ++e)
        t[e] = (short)f2bf(bf2f((ushort_t)t[e]) * sc2);
      aq[ni][kq] = t;
    }

  floatx4 oacc[2][4];
  float l_st[2] = {0.f, 0.f};
#pragma unroll
  for (int nb = 0; nb < 2; ++nb)
#pragma unroll
    for (int dvb = 0; dvb < 4; ++dvb) oacc[nb][dvb] = (floatx4){0.f,0.f,0.f,0.f};

  __syncthreads();   // tile 0 landed; all waves done reading Q from Ks[1]

  int cur = 0;
#pragma unroll 2
  for (int kt = 0; kt < 16; ++kt) {
    // issue next tile's stage into the other buffer (overlaps compute below)
    if (kt < 15) stage(kt + 1, cur ^ 1);

    // S^T = K * Q^T  (mi = kv block 0..7, ni = q block 0..1)
    floatx4 s[8][2];
#pragma unroll
    for (int mi = 0; mi < 8; ++mi) {
      s[mi][0] = (floatx4){0.f,0.f,0.f,0.f};
      s[mi][1] = (floatx4){0.f,0.f,0.f,0.f};
    }
    __builtin_amdgcn_s_setprio(1);
#pragma unroll
    for (int kq = 0; kq < 2; ++kq) {
      bf16x8 ak[8];
#pragma unroll
      for (int mi = 0; mi < 8; ++mi)
        ak[mi] = *(const bf16x8*)&Ks[cur][(mi * 16 + rq) * 64 + (((kq * 4 + kg) ^ (rq & 7)) * 8)];
#pragma unroll
      for (int mi = 0; mi < 8; ++mi)
#pragma unroll
        for (int ni = 0; ni < 2; ++ni)
          s[mi][ni] = mfma16(ak[mi], aq[ni][kq], s[mi][ni]);
    }
    __builtin_amdgcn_s_setprio(0);

    // p = 2^s ; per-lane partial row sums (registers only)
#pragma unroll
    for (int mi = 0; mi < 8; ++mi)
#pragma unroll
      for (int ni = 0; ni < 2; ++ni)
#pragma unroll
        for (int rr = 0; rr < 4; ++rr)
          s[mi][ni][rr] = __builtin_amdgcn_exp2f(s[mi][ni][rr]);
#pragma unroll
    for (int ni = 0; ni < 2; ++ni) {
      float t = 0.f;
#pragma unroll
      for (int mi = 0; mi < 8; ++mi)
        t += (s[mi][ni][0] + s[mi][ni][1]) + (s[mi][ni][2] + s[mi][ni][3]);
      l_st[ni] += t;
    }

    // O += P V : P packed from own s regs (sigma layout), V^T from LDS
    __builtin_amdgcn_s_setprio(1);
#pragma unroll
    for (int c = 0; c < 4; ++c) {
      bf16x8 vf[4];
#pragma unroll
      for (int dvb = 0; dvb < 4; ++dvb) {
        int dv = dvb * 16 + rq;
        int ch = (c * 4 + kg) ^ (rq & 7);
        vf[dvb] = *(const bf16x8*)&Vs[cur][dv * 128 + ch * 8];
      }
#pragma unroll
      for (int nb = 0; nb < 2; ++nb) {
        union { unsigned u[4]; bf16x8 v; } pa;
        pa.u[0] = pk2(s[2*c  ][nb][0], s[2*c  ][nb][1]);
        pa.u[1] = pk2(s[2*c  ][nb][2], s[2*c  ][nb][3]);
        pa.u[2] = pk2(s[2*c+1][nb][0], s[2*c+1][nb][1]);
        pa.u[3] = pk2(s[2*c+1][nb][2], s[2*c+1][nb][3]);
#pragma unroll
        for (int dvb = 0; dvb < 4; ++dvb)
          oacc[nb][dvb] = mfma16(pa.v, vf[dvb], oacc[nb][dvb]);
      }
    }
    __builtin_amdgcn_s_setprio(0);

    __syncthreads();   // next tile landed; all waves done with buf[cur]
    cur ^= 1;
  }

  // combine l across kg groups (each wave self-contained in q)
#pragma unroll
  for (int ni = 0; ni < 2; ++ni) {
    l_st[ni] += __shfl_xor(l_st[ni], 16, 64);
    l_st[ni] += __shfl_xor(l_st[ni], 32, 64);
  }
  if (lane < 16) {
    reds[wq * 32 + rq]      = l_st[0];
    reds[wq * 32 + 16 + rq] = l_st[1];
  }
  __syncthreads();

  // epilogue: Oh = Qh + O/l
#pragma unroll
  for (int nb = 0; nb < 2; ++nb)
#pragma unroll
    for (int rr = 0; rr < 4; ++rr) {
      int row = wq * 32 + nb * 16 + kg * 4 + rr;
      float linv = 1.0f / reds[row];
#pragma unroll
      for (int dvb = 0; dvb < 4; ++dvb) {
        int col = dvb * 16 + rq;
        size_t idx = qkbase + (size_t)(q0 + row) * 1024 + col;
        Ob[idx] = f2bf(oacc[nb][dvb][rr] * linv + bf2f(Qp[idx]));
      }
    }
}

// ---------------------------------------------------------------------------
extern "C" void kernel_launch(void* const* d_in, const int* in_sizes, int n_in,
                              void* d_out, int out_size, void* d_ws, size_t ws_size,
                              hipStream_t stream)
{
  const float* Q  = (const float*)d_in[0];
  const float* K  = (const float*)d_in[1];
  const float* Wq = (const float*)d_in[2];
  const float* bq = (const float*)d_in[3];
  const float* Wk = (const float*)d_in[4];
  const float* bk = (const float*)d_in[5];
  const float* Wv = (const float*)d_in[6];
  const float* bv = (const float*)d_in[7];
  const float* Wo = (const float*)d_in[8];
  const float* bo = (const float*)d_in[9];
  float* Out = (float*)d_out;

  ushort_t* ws = (ushort_t*)d_ws;
  const size_t E = (size_t)8192 * 1024;
  const size_t WSZ = (size_t)1024 * 1024;
  ushort_t* Qb  = ws;            // aliased by Ob after attention
  ushort_t* Kb  = ws + E;
  ushort_t* Qp  = ws + 2*E;
  ushort_t* Kp  = ws + 3*E;
  ushort_t* Vt  = ws + 4*E;      // bf16 V^T [1024][8192], sigma kv layout
  ushort_t* Wqb = ws + 5*E;
  ushort_t* Wkb = ws + 5*E + WSZ;
  ushort_t* Wvb = ws + 5*E + 2*WSZ;
  ushort_t* Wob = ws + 5*E + 3*WSZ;
  ushort_t* Ob  = Qb;

  cvt4<<<dim3(4096, 1, 2), 256, 0, stream>>>(Q, K, K, K, Qb, Kb, Kb, Kb, 1048576);
  cvt4<<<dim3(512, 1, 4), 256, 0, stream>>>(Wq, Wk, Wv, Wo, Wqb, Wkb, Wvb, Wob, 131072);

  dim3 blk(256);
  gemm_qkv<<<dim3(8, 64, 3), blk, 0, stream>>>(Qb, Kb, Wqb, Wkb, Wvb,
                                               bq, bk, bv, Qp, Kp, Vt);
  attn_kernel<<<dim3(16, 64), blk, 0, stream>>>(Qp, Kp, Vt, Ob);
  gemm_out<<<dim3(8, 64), blk, 0, stream>>>(Ob, Wob, bo, Out);
}

// Round 3
// 301.394 us; speedup vs baseline: 1.1058x; 1.0249x over previous
//
#include <hip/hip_runtime.h>
#include <cstddef>
#include <cstdint>

// ---------------------------------------------------------------------------
// MAB fused block. B=4 N=M=2048 C=1024 H=16 d=64. bf16 MFMA internally.
// R9: attention VALU diet. rocprof R8: VALUBusy 50% vs MfmaUtil 32% -> softmax
// VALU is the critical pipe. (1) row-sum l computed by MFMA with a ones
// B-operand (permutation-invariant under the sigma V layout): 8 extra MFMA/tile
// replace 64 v_add/tile AND the whole cross-lane epilogue reduction (shfl +
// reds LDS + barrier) -- l lands in-lane at exactly the epilogue's index.
// (2) P-pack via __builtin_convertvector -> compiler emits v_cvt_pk_bf16_f32
// (1 instr per pair instead of add+add+perm). (3) both cvt launches merged.
// R8 double-buffered 1-barrier-per-tile staging kept.
// ---------------------------------------------------------------------------

typedef unsigned short ushort_t;
typedef __attribute__((ext_vector_type(8))) short bf16x8;
typedef __attribute__((ext_vector_type(4))) float floatx4;
typedef __attribute__((ext_vector_type(2))) float f32x2;
typedef __attribute__((ext_vector_type(2))) __bf16 b16x2;
typedef __attribute__((ext_vector_type(4))) unsigned short us4;

__device__ __forceinline__ ushort_t f2bf(float x) {   // RNE
  union { float f; unsigned u; } v; v.f = x;
  unsigned r = v.u + 0x7FFFu + ((v.u >> 16) & 1u);
  return (ushort_t)(r >> 16);
}
__device__ __forceinline__ float bf2f(ushort_t x) {
  union { unsigned u; float f; } v; v.u = ((unsigned)x) << 16;
  return v.f;
}
// pack two f32 -> [bf16(b):bf16(a)] via +0x8000 + v_perm (round-half-up)
__device__ __forceinline__ unsigned pk2(float a, float b) {
  union { float f; unsigned u; } x, y; x.f = a; y.f = b;
  return __builtin_amdgcn_perm(y.u + 0x8000u, x.u + 0x8000u, 0x07060302u);
}
// pack two f32 -> bf16 pair via compiler (v_cvt_pk_bf16_f32, RNE)
__device__ __forceinline__ unsigned pk2c(float a, float b) {
  union { b16x2 v; unsigned u; } r;
  r.v = __builtin_convertvector((f32x2){a, b}, b16x2);
  return r.u;
}
__device__ __forceinline__ floatx4 mfma16(bf16x8 a, bf16x8 b, floatx4 c) {
  return __builtin_amdgcn_mfma_f32_16x16x32_bf16(a, b, c, 0, 0, 0);
}
__device__ __forceinline__ void gld_lds16(const void* g, void* l) {
  __builtin_amdgcn_global_load_lds(
      (const __attribute__((address_space(1))) unsigned int*)g,
      (__attribute__((address_space(3))) unsigned int*)l, 16, 0, 0);
}

// ---------------------------------------------------------------------------
// f32 -> bf16, 8 elems/thread, 6 tensors by blockIdx.z (Q,K,Wq,Wk,Wv,Wo).
// ---------------------------------------------------------------------------
__global__ void cvt6(const float* __restrict__ i0, const float* __restrict__ i1,
                     const float* __restrict__ i2, const float* __restrict__ i3,
                     const float* __restrict__ i4, const float* __restrict__ i5,
                     ushort_t* __restrict__ o0, ushort_t* __restrict__ o1,
                     ushort_t* __restrict__ o2, ushort_t* __restrict__ o3,
                     ushort_t* __restrict__ o4, ushort_t* __restrict__ o5) {
  int z = blockIdx.z;
  const float* in = z == 0 ? i0 : z == 1 ? i1 : z == 2 ? i2 : z == 3 ? i3 : z == 4 ? i4 : i5;
  ushort_t* out = z == 0 ? o0 : z == 1 ? o1 : z == 2 ? o2 : z == 3 ? o3 : z == 4 ? o4 : o5;
  int n8 = (z < 2) ? 1048576 : 131072;
  int i = blockIdx.x * 256 + threadIdx.x;
  if (i < n8) {
    const float4* p = (const float4*)in + (size_t)i * 2;
    float4 a = p[0], b = p[1];
    uint4 o;
    o.x = pk2(a.x, a.y); o.y = pk2(a.z, a.w);
    o.z = pk2(b.x, b.y); o.w = pk2(b.z, b.w);
    *((uint4*)out + i) = o;
  }
}

// ---------------------------------------------------------------------------
// Fused QKV projections. z=0: Qp; z=1: Kp; z=2: Vt (bf16, transposed
// [1024 dv][8192 kv], sigma-permuted within each 32-kv block).
// 128x128 tile, BK=64, 3-bit XOR chunk swizzle.
// ---------------------------------------------------------------------------
__global__ __launch_bounds__(256, 2)
void gemm_qkv(const ushort_t* __restrict__ Qb, const ushort_t* __restrict__ Kb,
              const ushort_t* __restrict__ Wqb, const ushort_t* __restrict__ Wkb,
              const ushort_t* __restrict__ Wvb,
              const float* __restrict__ bq, const float* __restrict__ bk,
              const float* __restrict__ bv,
              ushort_t* __restrict__ Qp, ushort_t* __restrict__ Kp,
              ushort_t* __restrict__ Vt)
{
  const int Kd = 1024, Nn = 1024;
  const int z = blockIdx.z;
  const ushort_t* Ab = (z == 0) ? Qb : Kb;
  const ushort_t* Bw = (z == 0) ? Wqb : (z == 1) ? Wkb : Wvb;
  const float* bias  = (z == 0) ? bq : (z == 1) ? bk : bv;

  __shared__ __align__(16) ushort_t As[128][64];
  __shared__ __align__(16) ushort_t Bs[128][64];
  const int tid = threadIdx.x;
  const int lane = tid & 63, wave = tid >> 6;
  const int wm = (wave >> 1) * 64, wn = (wave & 1) * 64;
  const int rq = lane & 15, kg = lane >> 4;
  const int row0 = blockIdx.y * 128, col0 = blockIdx.x * 128;

  const int st_sub = lane >> 3;                 // row within 8-row group
  const int st_cs  = (lane & 7) ^ st_sub;       // swizzled source 16B chunk

  floatx4 acc[4][4];
#pragma unroll
  for (int i = 0; i < 4; ++i)
#pragma unroll
    for (int j = 0; j < 4; ++j) acc[i][j] = (floatx4){0.f, 0.f, 0.f, 0.f};

  for (int k0 = 0; k0 < Kd; k0 += 64) {
    __syncthreads();
#pragma unroll
    for (int r = 0; r < 4; ++r) {
      int i = wave * 4 + r;                     // 0..15, 8 rows each
      int row = i * 8 + st_sub;
      gld_lds16(Ab + (size_t)(row0 + row) * Kd + k0 + st_cs * 8, (ushort_t*)As + i * 512);
      gld_lds16(Bw + (size_t)(col0 + row) * Kd + k0 + st_cs * 8, (ushort_t*)Bs + i * 512);
    }
    __syncthreads();
#pragma unroll
    for (int kq = 0; kq < 2; ++kq) {
      bf16x8 af[4], bfr[4];
#pragma unroll
      for (int mi = 0; mi < 4; ++mi)
        af[mi] = *(const bf16x8*)&As[wm + mi*16 + rq][((kq*4 + kg) ^ (rq & 7)) * 8];
#pragma unroll
      for (int ni = 0; ni < 4; ++ni)
        bfr[ni] = *(const bf16x8*)&Bs[wn + ni*16 + rq][((kq*4 + kg) ^ (rq & 7)) * 8];
#pragma unroll
      for (int mi = 0; mi < 4; ++mi)
#pragma unroll
        for (int ni = 0; ni < 4; ++ni)
          acc[mi][ni] = mfma16(af[mi], bfr[ni], acc[mi][ni]);
    }
  }

  float bv4[4];
#pragma unroll
  for (int ni = 0; ni < 4; ++ni) bv4[ni] = bias[col0 + wn + ni*16 + rq];

  if (z < 2) {
    ushort_t* Cb = (z == 0) ? Qp : Kp;
#pragma unroll
    for (int mi = 0; mi < 4; ++mi)
#pragma unroll
      for (int ni = 0; ni < 4; ++ni)
#pragma unroll
        for (int rr = 0; rr < 4; ++rr) {
          int row = row0 + wm + mi*16 + kg*4 + rr;
          int col = col0 + wn + ni*16 + rq;
          Cb[(size_t)row * Nn + col] = f2bf(acc[mi][ni][rr] + bv4[ni]);
        }
  } else {
    // sigma layout: kv = base32 + [hi kg1 kg0 r1 r0] stored at
    // position base32 + [kg1 kg0 hi r1 r0]  (hi = mi&1)
#pragma unroll
    for (int mi = 0; mi < 4; ++mi)
#pragma unroll
      for (int ni = 0; ni < 4; ++ni) {
        int col = col0 + wn + ni*16 + rq;       // dv
        int base32 = row0 + wm + (mi >> 1) * 32;
        int p = kg * 8 + (mi & 1) * 4;          // r 0..3 contiguous
        us4 o = { f2bf(acc[mi][ni][0] + bv4[ni]), f2bf(acc[mi][ni][1] + bv4[ni]),
                  f2bf(acc[mi][ni][2] + bv4[ni]), f2bf(acc[mi][ni][3] + bv4[ni]) };
        *(us4*)(Vt + (size_t)col * 8192 + base32 + p) = o;
      }
  }
}

// ---------------------------------------------------------------------------
// Output GEMM: out = bf2f(Ob) + relu(Ob*Wo^T + bo), f32 out. BK=64.
// ---------------------------------------------------------------------------
__global__ __launch_bounds__(256, 2)
void gemm_out(const ushort_t* __restrict__ Ob, const ushort_t* __restrict__ Bw,
              const float* __restrict__ bias, float* __restrict__ Out)
{
  const int Kd = 1024, Nn = 1024;
  __shared__ __align__(16) ushort_t As[128][64];
  __shared__ __align__(16) ushort_t Bs[128][64];
  const int tid = threadIdx.x;
  const int lane = tid & 63, wave = tid >> 6;
  const int wm = (wave >> 1) * 64, wn = (wave & 1) * 64;
  const int rq = lane & 15, kg = lane >> 4;
  const int row0 = blockIdx.y * 128, col0 = blockIdx.x * 128;

  const int st_sub = lane >> 3;
  const int st_cs  = (lane & 7) ^ st_sub;

  floatx4 acc[4][4];
#pragma unroll
  for (int i = 0; i < 4; ++i)
#pragma unroll
    for (int j = 0; j < 4; ++j) acc[i][j] = (floatx4){0.f, 0.f, 0.f, 0.f};

  for (int k0 = 0; k0 < Kd; k0 += 64) {
    __syncthreads();
#pragma unroll
    for (int r = 0; r < 4; ++r) {
      int i = wave * 4 + r;
      int row = i * 8 + st_sub;
      gld_lds16(Ob + (size_t)(row0 + row) * Kd + k0 + st_cs * 8, (ushort_t*)As + i * 512);
      gld_lds16(Bw + (size_t)(col0 + row) * Kd + k0 + st_cs * 8, (ushort_t*)Bs + i * 512);
    }
    __syncthreads();
#pragma unroll
    for (int kq = 0; kq < 2; ++kq) {
      bf16x8 af[4], bfr[4];
#pragma unroll
      for (int mi = 0; mi < 4; ++mi)
        af[mi] = *(const bf16x8*)&As[wm + mi*16 + rq][((kq*4 + kg) ^ (rq & 7)) * 8];
#pragma unroll
      for (int ni = 0; ni < 4; ++ni)
        bfr[ni] = *(const bf16x8*)&Bs[wn + ni*16 + rq][((kq*4 + kg) ^ (rq & 7)) * 8];
#pragma unroll
      for (int mi = 0; mi < 4; ++mi)
#pragma unroll
        for (int ni = 0; ni < 4; ++ni)
          acc[mi][ni] = mfma16(af[mi], bfr[ni], acc[mi][ni]);
    }
  }

  float bv4[4];
#pragma unroll
  for (int ni = 0; ni < 4; ++ni) bv4[ni] = bias[col0 + wn + ni*16 + rq];
#pragma unroll
  for (int mi = 0; mi < 4; ++mi)
#pragma unroll
    for (int ni = 0; ni < 4; ++ni)
#pragma unroll
      for (int rr = 0; rr < 4; ++rr) {
        int row = row0 + wm + mi*16 + kg*4 + rr;
        int col = col0 + wn + ni*16 + rq;
        size_t idx = (size_t)row * Nn + col;
        float pre = acc[mi][ni][rr] + bv4[ni];
        Out[idx] = bf2f(Ob[idx]) + (pre > 0.f ? pre : 0.f);
      }
}

// ---------------------------------------------------------------------------
// Flash attention (no-max softmax). BQ=128, BKV=128, d=64, all bf16.
// Wave w owns q rows [w*32, w*32+32); S^T = K*Q^T over the full 128-kv tile,
// softmax + P-pack entirely in registers, PV with P as in-register A-operand
// (sigma-layout V^T). Double-buffered staging, ONE barrier per K-tile.
// R9: row-sum l via mfma(pa, ones) -> lacc; in-lane epilogue (no shfl/reds).
// LDS: 2x(Ks 16K + Vs 16K) = 64 KB -> 2 blocks/CU.
// ---------------------------------------------------------------------------
__global__ __launch_bounds__(256, 2)
void attn_kernel(const ushort_t* __restrict__ Qp,
                 const ushort_t* __restrict__ Kp,
                 const ushort_t* __restrict__ Vt,
                 ushort_t* __restrict__ Ob)
{
  const float sc2 = 0.045084439f;  // (1/32) * log2(e)
  const int qt = blockIdx.x;       // 0..15
  const int bh = blockIdx.y;       // 0..63
  const int b = bh >> 4, h = bh & 15;
  const int q0 = qt * 128;

  __shared__ __align__(16) ushort_t Ks[2][8192];  // K[128][64] per buf
  __shared__ __align__(16) ushort_t Vs[2][8192];  // V^T[64][128] sigma, per buf

  const int tid = threadIdx.x, lane = tid & 63, wq = tid >> 6;  // wq: q-quarter
  const int rq = lane & 15, kg = lane >> 4;

  const size_t qkbase = (size_t)(b * 2048) * 1024 + h * 64;

  // per-lane staging geometry (shared by Q/K and V paths)
  const int sg_sub = lane >> 3;               // row within 8-row group
  const int sg_csk = (lane & 7) ^ sg_sub;     // swizzled 16B chunk (64-col row)

  // stage Q tile (128x64) into Ks[1]
#pragma unroll
  for (int r = 0; r < 4; ++r) {
    int i = wq * 4 + r;
    int row = i * 8 + sg_sub;
    gld_lds16(Qp + qkbase + (size_t)(q0 + row) * 1024 + sg_csk * 8, &Ks[1][i * 512]);
  }
  __syncthreads();

  auto stage = [&](int kt, int bufi) {
    const int kv0 = kt * 128;
#pragma unroll
    for (int r = 0; r < 4; ++r) {
      int i = wq * 4 + r;
      int rowk = i * 8 + sg_sub;
      gld_lds16(Kp + qkbase + (size_t)(kv0 + rowk) * 1024 + sg_csk * 8,
                &Ks[bufi][i * 512]);
      int dv = i * 4 + (lane >> 4);
      int csv = (lane & 15) ^ (dv & 7);
      gld_lds16(Vt + (size_t)(h * 64 + dv) * 8192 + b * 2048 + kv0 + csv * 8,
                &Vs[bufi][i * 512]);
    }
  };
  stage(0, 0);

  // preload Q B-frags scaled by sc2 from Ks[1]: aq[ni][kq], q = wq*32+ni*16+rq
  bf16x8 aq[2][2];
#pragma unroll
  for (int ni = 0; ni < 2; ++ni)
#pragma unroll
    for (int kq = 0; kq < 2; ++kq) {
      int row = wq * 32 + ni * 16 + rq;
      int ch = (kq * 4 + kg) ^ (rq & 7);
      bf16x8 t = *(const bf16x8*)&Ks[1][row * 64 + ch * 8];
#pragma unroll
      for (int e = 0; e < 8; ++e)
        t[e] = (short)f2bf(bf2f((ushort_t)t[e]) * sc2);
      aq[ni][kq] = t;
    }

  // ones B-operand for the l row-sum MFMA (permutation-invariant)
  bf16x8 ones;
#pragma unroll
  for (int e = 0; e < 8; ++e) ones[e] = (short)0x3F80;

  floatx4 oacc[2][4];
  floatx4 lacc[2];
#pragma unroll
  for (int nb = 0; nb < 2; ++nb) {
    lacc[nb] = (floatx4){0.f,0.f,0.f,0.f};
#pragma unroll
    for (int dvb = 0; dvb < 4; ++dvb) oacc[nb][dvb] = (floatx4){0.f,0.f,0.f,0.f};
  }

  __syncthreads();   // tile 0 landed; all waves done reading Q from Ks[1]

  int cur = 0;
#pragma unroll 2
  for (int kt = 0; kt < 16; ++kt) {
    // issue next tile's stage into the other buffer (overlaps compute below)
    if (kt < 15) stage(kt + 1, cur ^ 1);

    // S^T = K * Q^T  (mi = kv block 0..7, ni = q block 0..1)
    floatx4 s[8][2];
#pragma unroll
    for (int mi = 0; mi < 8; ++mi) {
      s[mi][0] = (floatx4){0.f,0.f,0.f,0.f};
      s[mi][1] = (floatx4){0.f,0.f,0.f,0.f};
    }
    __builtin_amdgcn_s_setprio(1);
#pragma unroll
    for (int kq = 0; kq < 2; ++kq) {
      bf16x8 ak[8];
#pragma unroll
      for (int mi = 0; mi < 8; ++mi)
        ak[mi] = *(const bf16x8*)&Ks[cur][(mi * 16 + rq) * 64 + (((kq * 4 + kg) ^ (rq & 7)) * 8)];
#pragma unroll
      for (int mi = 0; mi < 8; ++mi)
#pragma unroll
        for (int ni = 0; ni < 2; ++ni)
          s[mi][ni] = mfma16(ak[mi], aq[ni][kq], s[mi][ni]);
    }
    __builtin_amdgcn_s_setprio(0);

    // p = 2^s (registers only; row sums come from the l-MFMA below)
#pragma unroll
    for (int mi = 0; mi < 8; ++mi)
#pragma unroll
      for (int ni = 0; ni < 2; ++ni)
#pragma unroll
        for (int rr = 0; rr < 4; ++rr)
          s[mi][ni][rr] = __builtin_amdgcn_exp2f(s[mi][ni][rr]);

    // O += P V ; l += P 1 : P packed from own s regs (sigma layout)
    __builtin_amdgcn_s_setprio(1);
#pragma unroll
    for (int c = 0; c < 4; ++c) {
      bf16x8 vf[4];
#pragma unroll
      for (int dvb = 0; dvb < 4; ++dvb) {
        int dv = dvb * 16 + rq;
        int ch = (c * 4 + kg) ^ (rq & 7);
        vf[dvb] = *(const bf16x8*)&Vs[cur][dv * 128 + ch * 8];
      }
#pragma unroll
      for (int nb = 0; nb < 2; ++nb) {
        union { unsigned u[4]; bf16x8 v; } pa;
        pa.u[0] = pk2c(s[2*c  ][nb][0], s[2*c  ][nb][1]);
        pa.u[1] = pk2c(s[2*c  ][nb][2], s[2*c  ][nb][3]);
        pa.u[2] = pk2c(s[2*c+1][nb][0], s[2*c+1][nb][1]);
        pa.u[3] = pk2c(s[2*c+1][nb][2], s[2*c+1][nb][3]);
#pragma unroll
        for (int dvb = 0; dvb < 4; ++dvb)
          oacc[nb][dvb] = mfma16(pa.v, vf[dvb], oacc[nb][dvb]);
        lacc[nb] = mfma16(pa.v, ones, lacc[nb]);
      }
    }
    __builtin_amdgcn_s_setprio(0);

    __syncthreads();   // next tile landed; all waves done with buf[cur]
    cur ^= 1;
  }

  // epilogue: Oh = Qh + O/l ; l is in-lane at exactly the row we store
#pragma unroll
  for (int nb = 0; nb < 2; ++nb)
#pragma unroll
    for (int rr = 0; rr < 4; ++rr) {
      int row = wq * 32 + nb * 16 + kg * 4 + rr;
      float linv = 1.0f / lacc[nb][rr];
#pragma unroll
      for (int dvb = 0; dvb < 4; ++dvb) {
        int col = dvb * 16 + rq;
        size_t idx = qkbase + (size_t)(q0 + row) * 1024 + col;
        Ob[idx] = f2bf(oacc[nb][dvb][rr] * linv + bf2f(Qp[idx]));
      }
    }
}

// ---------------------------------------------------------------------------
extern "C" void kernel_launch(void* const* d_in, const int* in_sizes, int n_in,
                              void* d_out, int out_size, void* d_ws, size_t ws_size,
                              hipStream_t stream)
{
  const float* Q  = (const float*)d_in[0];
  const float* K  = (const float*)d_in[1];
  const float* Wq = (const float*)d_in[2];
  const float* bq = (const float*)d_in[3];
  const float* Wk = (const float*)d_in[4];
  const float* bk = (const float*)d_in[5];
  const float* Wv = (const float*)d_in[6];
  const float* bv = (const float*)d_in[7];
  const float* Wo = (const float*)d_in[8];
  const float* bo = (const float*)d_in[9];
  float* Out = (float*)d_out;

  ushort_t* ws = (ushort_t*)d_ws;
  const size_t E = (size_t)8192 * 1024;
  const size_t WSZ = (size_t)1024 * 1024;
  ushort_t* Qb  = ws;            // aliased by Ob after attention
  ushort_t* Kb  = ws + E;
  ushort_t* Qp  = ws + 2*E;
  ushort_t* Kp  = ws + 3*E;
  ushort_t* Vt  = ws + 4*E;      // bf16 V^T [1024][8192], sigma kv layout
  ushort_t* Wqb = ws + 5*E;
  ushort_t* Wkb = ws + 5*E + WSZ;
  ushort_t* Wvb = ws + 5*E + 2*WSZ;
  ushort_t* Wob = ws + 5*E + 3*WSZ;
  ushort_t* Ob  = Qb;

  cvt6<<<dim3(4096, 1, 6), 256, 0, stream>>>(Q, K, Wq, Wk, Wv, Wo,
                                             Qb, Kb, Wqb, Wkb, Wvb, Wob);

  dim3 blk(256);
  gemm_qkv<<<dim3(8, 64, 3), blk, 0, stream>>>(Qb, Kb, Wqb, Wkb, Wvb,
                                               bq, bk, bv, Qp, Kp, Vt);
  attn_kernel<<<dim3(16, 64), blk, 0, stream>>>(Qp, Kp, Vt, Ob);
  gemm_out<<<dim3(8, 64), blk, 0, stream>>>(Ob, Wob, bo, Out);
}

// Round 4
// 300.628 us; speedup vs baseline: 1.1087x; 1.0025x over previous
//
#include <hip/hip_runtime.h>
#include <cstddef>
#include <cstdint>

// ---------------------------------------------------------------------------
// MAB fused block. B=4 N=M=2048 C=1024 H=16 d=64. bf16 MFMA internally.
// R10: break the MFMA/VALU phase-lockstep in attention. R9 counters: MfmaUtil
// 41 + VALUBusy 41 ~= 82 -> pipes mutually exclusive (exp2 phase leaves the
// matrix pipe idle). (1) PV restructured into 4 kv-32 chunks; exp2 of chunk
// c+1 is issued AFTER chunk c's MFMAs -> VALU work executes under the MFMA
// pipe's shadow (separate pipes, in-order issue doesn't block). (2) s-init
// v_movs eliminated: kq=0 S-MFMAs use a loop-invariant zero C operand (zf),
// so the 64 per-tile zeroing movs disappear. Everything else from R9 kept
// (dbuf 1-barrier staging, l-via-MFMA-ones, cvt_pk pack, sigma V^T layout).
// ---------------------------------------------------------------------------

typedef unsigned short ushort_t;
typedef __attribute__((ext_vector_type(8))) short bf16x8;
typedef __attribute__((ext_vector_type(4))) float floatx4;
typedef __attribute__((ext_vector_type(2))) float f32x2;
typedef __attribute__((ext_vector_type(2))) __bf16 b16x2;
typedef __attribute__((ext_vector_type(4))) unsigned short us4;

__device__ __forceinline__ ushort_t f2bf(float x) {   // RNE
  union { float f; unsigned u; } v; v.f = x;
  unsigned r = v.u + 0x7FFFu + ((v.u >> 16) & 1u);
  return (ushort_t)(r >> 16);
}
__device__ __forceinline__ float bf2f(ushort_t x) {
  union { unsigned u; float f; } v; v.u = ((unsigned)x) << 16;
  return v.f;
}
// pack two f32 -> [bf16(b):bf16(a)] via +0x8000 + v_perm (round-half-up)
__device__ __forceinline__ unsigned pk2(float a, float b) {
  union { float f; unsigned u; } x, y; x.f = a; y.f = b;
  return __builtin_amdgcn_perm(y.u + 0x8000u, x.u + 0x8000u, 0x07060302u);
}
// pack two f32 -> bf16 pair via compiler (v_cvt_pk_bf16_f32, RNE)
__device__ __forceinline__ unsigned pk2c(float a, float b) {
  union { b16x2 v; unsigned u; } r;
  r.v = __builtin_convertvector((f32x2){a, b}, b16x2);
  return r.u;
}
__device__ __forceinline__ floatx4 mfma16(bf16x8 a, bf16x8 b, floatx4 c) {
  return __builtin_amdgcn_mfma_f32_16x16x32_bf16(a, b, c, 0, 0, 0);
}
__device__ __forceinline__ void gld_lds16(const void* g, void* l) {
  __builtin_amdgcn_global_load_lds(
      (const __attribute__((address_space(1))) unsigned int*)g,
      (__attribute__((address_space(3))) unsigned int*)l, 16, 0, 0);
}

// ---------------------------------------------------------------------------
// f32 -> bf16, 8 elems/thread, 6 tensors by blockIdx.z (Q,K,Wq,Wk,Wv,Wo).
// ---------------------------------------------------------------------------
__global__ void cvt6(const float* __restrict__ i0, const float* __restrict__ i1,
                     const float* __restrict__ i2, const float* __restrict__ i3,
                     const float* __restrict__ i4, const float* __restrict__ i5,
                     ushort_t* __restrict__ o0, ushort_t* __restrict__ o1,
                     ushort_t* __restrict__ o2, ushort_t* __restrict__ o3,
                     ushort_t* __restrict__ o4, ushort_t* __restrict__ o5) {
  int z = blockIdx.z;
  const float* in = z == 0 ? i0 : z == 1 ? i1 : z == 2 ? i2 : z == 3 ? i3 : z == 4 ? i4 : i5;
  ushort_t* out = z == 0 ? o0 : z == 1 ? o1 : z == 2 ? o2 : z == 3 ? o3 : z == 4 ? o4 : o5;
  int n8 = (z < 2) ? 1048576 : 131072;
  int i = blockIdx.x * 256 + threadIdx.x;
  if (i < n8) {
    const float4* p = (const float4*)in + (size_t)i * 2;
    float4 a = p[0], b = p[1];
    uint4 o;
    o.x = pk2(a.x, a.y); o.y = pk2(a.z, a.w);
    o.z = pk2(b.x, b.y); o.w = pk2(b.z, b.w);
    *((uint4*)out + i) = o;
  }
}

// ---------------------------------------------------------------------------
// Fused QKV projections. z=0: Qp; z=1: Kp; z=2: Vt (bf16, transposed
// [1024 dv][8192 kv], sigma-permuted within each 32-kv block).
// 128x128 tile, BK=64, 3-bit XOR chunk swizzle.
// ---------------------------------------------------------------------------
__global__ __launch_bounds__(256, 2)
void gemm_qkv(const ushort_t* __restrict__ Qb, const ushort_t* __restrict__ Kb,
              const ushort_t* __restrict__ Wqb, const ushort_t* __restrict__ Wkb,
              const ushort_t* __restrict__ Wvb,
              const float* __restrict__ bq, const float* __restrict__ bk,
              const float* __restrict__ bv,
              ushort_t* __restrict__ Qp, ushort_t* __restrict__ Kp,
              ushort_t* __restrict__ Vt)
{
  const int Kd = 1024, Nn = 1024;
  const int z = blockIdx.z;
  const ushort_t* Ab = (z == 0) ? Qb : Kb;
  const ushort_t* Bw = (z == 0) ? Wqb : (z == 1) ? Wkb : Wvb;
  const float* bias  = (z == 0) ? bq : (z == 1) ? bk : bv;

  __shared__ __align__(16) ushort_t As[128][64];
  __shared__ __align__(16) ushort_t Bs[128][64];
  const int tid = threadIdx.x;
  const int lane = tid & 63, wave = tid >> 6;
  const int wm = (wave >> 1) * 64, wn = (wave & 1) * 64;
  const int rq = lane & 15, kg = lane >> 4;
  const int row0 = blockIdx.y * 128, col0 = blockIdx.x * 128;

  const int st_sub = lane >> 3;                 // row within 8-row group
  const int st_cs  = (lane & 7) ^ st_sub;       // swizzled source 16B chunk

  floatx4 acc[4][4];
#pragma unroll
  for (int i = 0; i < 4; ++i)
#pragma unroll
    for (int j = 0; j < 4; ++j) acc[i][j] = (floatx4){0.f, 0.f, 0.f, 0.f};

  for (int k0 = 0; k0 < Kd; k0 += 64) {
    __syncthreads();
#pragma unroll
    for (int r = 0; r < 4; ++r) {
      int i = wave * 4 + r;                     // 0..15, 8 rows each
      int row = i * 8 + st_sub;
      gld_lds16(Ab + (size_t)(row0 + row) * Kd + k0 + st_cs * 8, (ushort_t*)As + i * 512);
      gld_lds16(Bw + (size_t)(col0 + row) * Kd + k0 + st_cs * 8, (ushort_t*)Bs + i * 512);
    }
    __syncthreads();
#pragma unroll
    for (int kq = 0; kq < 2; ++kq) {
      bf16x8 af[4], bfr[4];
#pragma unroll
      for (int mi = 0; mi < 4; ++mi)
        af[mi] = *(const bf16x8*)&As[wm + mi*16 + rq][((kq*4 + kg) ^ (rq & 7)) * 8];
#pragma unroll
      for (int ni = 0; ni < 4; ++ni)
        bfr[ni] = *(const bf16x8*)&Bs[wn + ni*16 + rq][((kq*4 + kg) ^ (rq & 7)) * 8];
#pragma unroll
      for (int mi = 0; mi < 4; ++mi)
#pragma unroll
        for (int ni = 0; ni < 4; ++ni)
          acc[mi][ni] = mfma16(af[mi], bfr[ni], acc[mi][ni]);
    }
  }

  float bv4[4];
#pragma unroll
  for (int ni = 0; ni < 4; ++ni) bv4[ni] = bias[col0 + wn + ni*16 + rq];

  if (z < 2) {
    ushort_t* Cb = (z == 0) ? Qp : Kp;
#pragma unroll
    for (int mi = 0; mi < 4; ++mi)
#pragma unroll
      for (int ni = 0; ni < 4; ++ni)
#pragma unroll
        for (int rr = 0; rr < 4; ++rr) {
          int row = row0 + wm + mi*16 + kg*4 + rr;
          int col = col0 + wn + ni*16 + rq;
          Cb[(size_t)row * Nn + col] = f2bf(acc[mi][ni][rr] + bv4[ni]);
        }
  } else {
    // sigma layout: kv = base32 + [hi kg1 kg0 r1 r0] stored at
    // position base32 + [kg1 kg0 hi r1 r0]  (hi = mi&1)
#pragma unroll
    for (int mi = 0; mi < 4; ++mi)
#pragma unroll
      for (int ni = 0; ni < 4; ++ni) {
        int col = col0 + wn + ni*16 + rq;       // dv
        int base32 = row0 + wm + (mi >> 1) * 32;
        int p = kg * 8 + (mi & 1) * 4;          // r 0..3 contiguous
        us4 o = { f2bf(acc[mi][ni][0] + bv4[ni]), f2bf(acc[mi][ni][1] + bv4[ni]),
                  f2bf(acc[mi][ni][2] + bv4[ni]), f2bf(acc[mi][ni][3] + bv4[ni]) };
        *(us4*)(Vt + (size_t)col * 8192 + base32 + p) = o;
      }
  }
}

// ---------------------------------------------------------------------------
// Output GEMM: out = bf2f(Ob) + relu(Ob*Wo^T + bo), f32 out. BK=64.
// ---------------------------------------------------------------------------
__global__ __launch_bounds__(256, 2)
void gemm_out(const ushort_t* __restrict__ Ob, const ushort_t* __restrict__ Bw,
              const float* __restrict__ bias, float* __restrict__ Out)
{
  const int Kd = 1024, Nn = 1024;
  __shared__ __align__(16) ushort_t As[128][64];
  __shared__ __align__(16) ushort_t Bs[128][64];
  const int tid = threadIdx.x;
  const int lane = tid & 63, wave = tid >> 6;
  const int wm = (wave >> 1) * 64, wn = (wave & 1) * 64;
  const int rq = lane & 15, kg = lane >> 4;
  const int row0 = blockIdx.y * 128, col0 = blockIdx.x * 128;

  const int st_sub = lane >> 3;
  const int st_cs  = (lane & 7) ^ st_sub;

  floatx4 acc[4][4];
#pragma unroll
  for (int i = 0; i < 4; ++i)
#pragma unroll
    for (int j = 0; j < 4; ++j) acc[i][j] = (floatx4){0.f, 0.f, 0.f, 0.f};

  for (int k0 = 0; k0 < Kd; k0 += 64) {
    __syncthreads();
#pragma unroll
    for (int r = 0; r < 4; ++r) {
      int i = wave * 4 + r;
      int row = i * 8 + st_sub;
      gld_lds16(Ob + (size_t)(row0 + row) * Kd + k0 + st_cs * 8, (ushort_t*)As + i * 512);
      gld_lds16(Bw + (size_t)(col0 + row) * Kd + k0 + st_cs * 8, (ushort_t*)Bs + i * 512);
    }
    __syncthreads();
#pragma unroll
    for (int kq = 0; kq < 2; ++kq) {
      bf16x8 af[4], bfr[4];
#pragma unroll
      for (int mi = 0; mi < 4; ++mi)
        af[mi] = *(const bf16x8*)&As[wm + mi*16 + rq][((kq*4 + kg) ^ (rq & 7)) * 8];
#pragma unroll
      for (int ni = 0; ni < 4; ++ni)
        bfr[ni] = *(const bf16x8*)&Bs[wn + ni*16 + rq][((kq*4 + kg) ^ (rq & 7)) * 8];
#pragma unroll
      for (int mi = 0; mi < 4; ++mi)
#pragma unroll
        for (int ni = 0; ni < 4; ++ni)
          acc[mi][ni] = mfma16(af[mi], bfr[ni], acc[mi][ni]);
    }
  }

  float bv4[4];
#pragma unroll
  for (int ni = 0; ni < 4; ++ni) bv4[ni] = bias[col0 + wn + ni*16 + rq];
#pragma unroll
  for (int mi = 0; mi < 4; ++mi)
#pragma unroll
    for (int ni = 0; ni < 4; ++ni)
#pragma unroll
      for (int rr = 0; rr < 4; ++rr) {
        int row = row0 + wm + mi*16 + kg*4 + rr;
        int col = col0 + wn + ni*16 + rq;
        size_t idx = (size_t)row * Nn + col;
        float pre = acc[mi][ni][rr] + bv4[ni];
        Out[idx] = bf2f(Ob[idx]) + (pre > 0.f ? pre : 0.f);
      }
}

// ---------------------------------------------------------------------------
// Flash attention (no-max softmax). BQ=128, BKV=128, d=64, all bf16.
// Wave w owns q rows [w*32, w*32+32); S^T = K*Q^T over the full 128-kv tile,
// softmax + P-pack in registers, PV with P as in-register A-operand (sigma
// V^T). Double-buffered staging, ONE barrier per K-tile.
// R10: PV chunked by kv-32; exp2 of chunk c+1 issued after chunk c's MFMAs
// (VALU under MFMA shadow). kq=0 S-MFMAs take zero-C (no per-tile s zeroing).
// LDS: 2x(Ks 16K + Vs 16K) = 64 KB -> 2 blocks/CU.
// ---------------------------------------------------------------------------
__global__ __launch_bounds__(256, 2)
void attn_kernel(const ushort_t* __restrict__ Qp,
                 const ushort_t* __restrict__ Kp,
                 const ushort_t* __restrict__ Vt,
                 ushort_t* __restrict__ Ob)
{
  const float sc2 = 0.045084439f;  // (1/32) * log2(e)
  const int qt = blockIdx.x;       // 0..15
  const int bh = blockIdx.y;       // 0..63
  const int b = bh >> 4, h = bh & 15;
  const int q0 = qt * 128;

  __shared__ __align__(16) ushort_t Ks[2][8192];  // K[128][64] per buf
  __shared__ __align__(16) ushort_t Vs[2][8192];  // V^T[64][128] sigma, per buf

  const int tid = threadIdx.x, lane = tid & 63, wq = tid >> 6;  // wq: q-quarter
  const int rq = lane & 15, kg = lane >> 4;

  const size_t qkbase = (size_t)(b * 2048) * 1024 + h * 64;

  // per-lane staging geometry (shared by Q/K and V paths)
  const int sg_sub = lane >> 3;               // row within 8-row group
  const int sg_csk = (lane & 7) ^ sg_sub;     // swizzled 16B chunk (64-col row)

  // stage Q tile (128x64) into Ks[1]
#pragma unroll
  for (int r = 0; r < 4; ++r) {
    int i = wq * 4 + r;
    int row = i * 8 + sg_sub;
    gld_lds16(Qp + qkbase + (size_t)(q0 + row) * 1024 + sg_csk * 8, &Ks[1][i * 512]);
  }
  __syncthreads();

  auto stage = [&](int kt, int bufi) {
    const int kv0 = kt * 128;
#pragma unroll
    for (int r = 0; r < 4; ++r) {
      int i = wq * 4 + r;
      int rowk = i * 8 + sg_sub;
      gld_lds16(Kp + qkbase + (size_t)(kv0 + rowk) * 1024 + sg_csk * 8,
                &Ks[bufi][i * 512]);
      int dv = i * 4 + (lane >> 4);
      int csv = (lane & 15) ^ (dv & 7);
      gld_lds16(Vt + (size_t)(h * 64 + dv) * 8192 + b * 2048 + kv0 + csv * 8,
                &Vs[bufi][i * 512]);
    }
  };
  stage(0, 0);

  // preload Q B-frags scaled by sc2 from Ks[1]: aq[ni][kq], q = wq*32+ni*16+rq
  bf16x8 aq[2][2];
#pragma unroll
  for (int ni = 0; ni < 2; ++ni)
#pragma unroll
    for (int kq = 0; kq < 2; ++kq) {
      int row = wq * 32 + ni * 16 + rq;
      int ch = (kq * 4 + kg) ^ (rq & 7);
      bf16x8 t = *(const bf16x8*)&Ks[1][row * 64 + ch * 8];
#pragma unroll
      for (int e = 0; e < 8; ++e)
        t[e] = (short)f2bf(bf2f((ushort_t)t[e]) * sc2);
      aq[ni][kq] = t;
    }

  // ones B-operand for the l row-sum MFMA (permutation-invariant)
  bf16x8 ones;
#pragma unroll
  for (int e = 0; e < 8; ++e) ones[e] = (short)0x3F80;

  const floatx4 zf = (floatx4){0.f, 0.f, 0.f, 0.f};  // loop-invariant zero C

  floatx4 oacc[2][4];
  floatx4 lacc[2];
#pragma unroll
  for (int nb = 0; nb < 2; ++nb) {
    lacc[nb] = (floatx4){0.f,0.f,0.f,0.f};
#pragma unroll
    for (int dvb = 0; dvb < 4; ++dvb) oacc[nb][dvb] = (floatx4){0.f,0.f,0.f,0.f};
  }

  __syncthreads();   // tile 0 landed; all waves done reading Q from Ks[1]

  int cur = 0;
#pragma unroll 2
  for (int kt = 0; kt < 16; ++kt) {
    // issue next tile's stage into the other buffer (overlaps compute below)
    if (kt < 15) stage(kt + 1, cur ^ 1);

    // S^T = K * Q^T  (mi = kv block 0..7, ni = q block 0..1)
    floatx4 s[8][2];
    __builtin_amdgcn_s_setprio(1);
    {
      bf16x8 ak[8];
#pragma unroll
      for (int mi = 0; mi < 8; ++mi)
        ak[mi] = *(const bf16x8*)&Ks[cur][(mi * 16 + rq) * 64 + ((kg ^ (rq & 7)) * 8)];
#pragma unroll
      for (int mi = 0; mi < 8; ++mi)
#pragma unroll
        for (int ni = 0; ni < 2; ++ni)
          s[mi][ni] = mfma16(ak[mi], aq[ni][0], zf);      // zero-C, no v_movs
#pragma unroll
      for (int mi = 0; mi < 8; ++mi)
        ak[mi] = *(const bf16x8*)&Ks[cur][(mi * 16 + rq) * 64 + (((4 + kg) ^ (rq & 7)) * 8)];
#pragma unroll
      for (int mi = 0; mi < 8; ++mi)
#pragma unroll
        for (int ni = 0; ni < 2; ++ni)
          s[mi][ni] = mfma16(ak[mi], aq[ni][1], s[mi][ni]);
    }
    __builtin_amdgcn_s_setprio(0);

    // exp chunk 0 (mi 0,1); remaining chunks overlap PV MFMAs below
#pragma unroll
    for (int mi = 0; mi < 2; ++mi)
#pragma unroll
      for (int ni = 0; ni < 2; ++ni)
#pragma unroll
        for (int rr = 0; rr < 4; ++rr)
          s[mi][ni][rr] = __builtin_amdgcn_exp2f(s[mi][ni][rr]);

    // O += P V ; l += P 1 : per kv-32 chunk c: pack -> MFMA -> exp(next chunk)
#pragma unroll
    for (int c = 0; c < 4; ++c) {
      bf16x8 vf[4];
#pragma unroll
      for (int dvb = 0; dvb < 4; ++dvb) {
        int dv = dvb * 16 + rq;
        int ch = (c * 4 + kg) ^ (rq & 7);
        vf[dvb] = *(const bf16x8*)&Vs[cur][dv * 128 + ch * 8];
      }
      union { unsigned u[4]; bf16x8 v; } pa0, pa1;
      pa0.u[0] = pk2c(s[2*c  ][0][0], s[2*c  ][0][1]);
      pa0.u[1] = pk2c(s[2*c  ][0][2], s[2*c  ][0][3]);
      pa0.u[2] = pk2c(s[2*c+1][0][0], s[2*c+1][0][1]);
      pa0.u[3] = pk2c(s[2*c+1][0][2], s[2*c+1][0][3]);
      pa1.u[0] = pk2c(s[2*c  ][1][0], s[2*c  ][1][1]);
      pa1.u[1] = pk2c(s[2*c  ][1][2], s[2*c  ][1][3]);
      pa1.u[2] = pk2c(s[2*c+1][1][0], s[2*c+1][1][1]);
      pa1.u[3] = pk2c(s[2*c+1][1][2], s[2*c+1][1][3]);
      __builtin_amdgcn_s_setprio(1);
#pragma unroll
      for (int dvb = 0; dvb < 4; ++dvb) {
        oacc[0][dvb] = mfma16(pa0.v, vf[dvb], oacc[0][dvb]);
        oacc[1][dvb] = mfma16(pa1.v, vf[dvb], oacc[1][dvb]);
      }
      lacc[0] = mfma16(pa0.v, ones, lacc[0]);
      lacc[1] = mfma16(pa1.v, ones, lacc[1]);
      __builtin_amdgcn_s_setprio(0);
      if (c < 3) {   // exp of next chunk issues while PV(c) MFMAs execute
#pragma unroll
        for (int mi = 2*c + 2; mi < 2*c + 4; ++mi)
#pragma unroll
          for (int ni = 0; ni < 2; ++ni)
#pragma unroll
            for (int rr = 0; rr < 4; ++rr)
              s[mi][ni][rr] = __builtin_amdgcn_exp2f(s[mi][ni][rr]);
      }
    }

    __syncthreads();   // next tile landed; all waves done with buf[cur]
    cur ^= 1;
  }

  // epilogue: Oh = Qh + O/l ; l is in-lane at exactly the row we store
#pragma unroll
  for (int nb = 0; nb < 2; ++nb)
#pragma unroll
    for (int rr = 0; rr < 4; ++rr) {
      int row = wq * 32 + nb * 16 + kg * 4 + rr;
      float linv = 1.0f / lacc[nb][rr];
#pragma unroll
      for (int dvb = 0; dvb < 4; ++dvb) {
        int col = dvb * 16 + rq;
        size_t idx = qkbase + (size_t)(q0 + row) * 1024 + col;
        Ob[idx] = f2bf(oacc[nb][dvb][rr] * linv + bf2f(Qp[idx]));
      }
    }
}

// ---------------------------------------------------------------------------
extern "C" void kernel_launch(void* const* d_in, const int* in_sizes, int n_in,
                              void* d_out, int out_size, void* d_ws, size_t ws_size,
                              hipStream_t stream)
{
  const float* Q  = (const float*)d_in[0];
  const float* K  = (const float*)d_in[1];
  const float* Wq = (const float*)d_in[2];
  const float* bq = (const float*)d_in[3];
  const float* Wk = (const float*)d_in[4];
  const float* bk = (const float*)d_in[5];
  const float* Wv = (const float*)d_in[6];
  const float* bv = (const float*)d_in[7];
  const float* Wo = (const float*)d_in[8];
  const float* bo = (const float*)d_in[9];
  float* Out = (float*)d_out;

  ushort_t* ws = (ushort_t*)d_ws;
  const size_t E = (size_t)8192 * 1024;
  const size_t WSZ = (size_t)1024 * 1024;
  ushort_t* Qb  = ws;            // aliased by Ob after attention
  ushort_t* Kb  = ws + E;
  ushort_t* Qp  = ws + 2*E;
  ushort_t* Kp  = ws + 3*E;
  ushort_t* Vt  = ws + 4*E;      // bf16 V^T [1024][8192], sigma kv layout
  ushort_t* Wqb = ws + 5*E;
  ushort_t* Wkb = ws + 5*E + WSZ;
  ushort_t* Wvb = ws + 5*E + 2*WSZ;
  ushort_t* Wob = ws + 5*E + 3*WSZ;
  ushort_t* Ob  = Qb;

  cvt6<<<dim3(4096, 1, 6), 256, 0, stream>>>(Q, K, Wq, Wk, Wv, Wo,
                                             Qb, Kb, Wqb, Wkb, Wvb, Wob);

  dim3 blk(256);
  gemm_qkv<<<dim3(8, 64, 3), blk, 0, stream>>>(Qb, Kb, Wqb, Wkb, Wvb,
                                               bq, bk, bv, Qp, Kp, Vt);
  attn_kernel<<<dim3(16, 64), blk, 0, stream>>>(Qp, Kp, Vt, Ob);
  gemm_out<<<dim3(8, 64), blk, 0, stream>>>(Ob, Wob, bo, Out);
}

// Round 5
// 285.026 us; speedup vs baseline: 1.1694x; 1.0547x over previous
//
#include <hip/hip_runtime.h>
#include <cstddef>
#include <cstdint>

// ---------------------------------------------------------------------------
// MAB fused block. B=4 N=M=2048 C=1024 H=16 d=64. bf16 MFMA internally.
// R11: XCD-aware block swizzle (T1) on attn + both GEMMs. R10 counters:
// attn FETCH 147.5 MB vs ~80 ideal -> K/V panels re-fetched per XCD because
// qt-major dispatch round-robins same-bh blocks over the 8 private L2s; the
// per-tile barrier drain is HBM-latency-class as a result. Swizzle: xcd=wg&7
// owns contiguous work sharing panels (attn: 8 bh x 16 qt; gemm: 8-row A
// stripe x 8 cols), making drains L2-latency-class. Bijective (grids are
// multiples of 8). R10 attn structure otherwise unchanged.
// ---------------------------------------------------------------------------

typedef unsigned short ushort_t;
typedef __attribute__((ext_vector_type(8))) short bf16x8;
typedef __attribute__((ext_vector_type(4))) float floatx4;
typedef __attribute__((ext_vector_type(2))) float f32x2;
typedef __attribute__((ext_vector_type(2))) __bf16 b16x2;
typedef __attribute__((ext_vector_type(4))) unsigned short us4;

__device__ __forceinline__ ushort_t f2bf(float x) {   // RNE
  union { float f; unsigned u; } v; v.f = x;
  unsigned r = v.u + 0x7FFFu + ((v.u >> 16) & 1u);
  return (ushort_t)(r >> 16);
}
__device__ __forceinline__ float bf2f(ushort_t x) {
  union { unsigned u; float f; } v; v.u = ((unsigned)x) << 16;
  return v.f;
}
// pack two f32 -> [bf16(b):bf16(a)] via +0x8000 + v_perm (round-half-up)
__device__ __forceinline__ unsigned pk2(float a, float b) {
  union { float f; unsigned u; } x, y; x.f = a; y.f = b;
  return __builtin_amdgcn_perm(y.u + 0x8000u, x.u + 0x8000u, 0x07060302u);
}
// pack two f32 -> bf16 pair via compiler (v_cvt_pk_bf16_f32, RNE)
__device__ __forceinline__ unsigned pk2c(float a, float b) {
  union { b16x2 v; unsigned u; } r;
  r.v = __builtin_convertvector((f32x2){a, b}, b16x2);
  return r.u;
}
__device__ __forceinline__ floatx4 mfma16(bf16x8 a, bf16x8 b, floatx4 c) {
  return __builtin_amdgcn_mfma_f32_16x16x32_bf16(a, b, c, 0, 0, 0);
}
__device__ __forceinline__ void gld_lds16(const void* g, void* l) {
  __builtin_amdgcn_global_load_lds(
      (const __attribute__((address_space(1))) unsigned int*)g,
      (__attribute__((address_space(3))) unsigned int*)l, 16, 0, 0);
}

// ---------------------------------------------------------------------------
// f32 -> bf16, 8 elems/thread, 6 tensors by blockIdx.z (Q,K,Wq,Wk,Wv,Wo).
// ---------------------------------------------------------------------------
__global__ void cvt6(const float* __restrict__ i0, const float* __restrict__ i1,
                     const float* __restrict__ i2, const float* __restrict__ i3,
                     const float* __restrict__ i4, const float* __restrict__ i5,
                     ushort_t* __restrict__ o0, ushort_t* __restrict__ o1,
                     ushort_t* __restrict__ o2, ushort_t* __restrict__ o3,
                     ushort_t* __restrict__ o4, ushort_t* __restrict__ o5) {
  int z = blockIdx.z;
  const float* in = z == 0 ? i0 : z == 1 ? i1 : z == 2 ? i2 : z == 3 ? i3 : z == 4 ? i4 : i5;
  ushort_t* out = z == 0 ? o0 : z == 1 ? o1 : z == 2 ? o2 : z == 3 ? o3 : z == 4 ? o4 : o5;
  int n8 = (z < 2) ? 1048576 : 131072;
  int i = blockIdx.x * 256 + threadIdx.x;
  if (i < n8) {
    const float4* p = (const float4*)in + (size_t)i * 2;
    float4 a = p[0], b = p[1];
    uint4 o;
    o.x = pk2(a.x, a.y); o.y = pk2(a.z, a.w);
    o.z = pk2(b.x, b.y); o.w = pk2(b.z, b.w);
    *((uint4*)out + i) = o;
  }
}

// ---------------------------------------------------------------------------
// Fused QKV projections. z=0: Qp; z=1: Kp; z=2: Vt (bf16, transposed
// [1024 dv][8192 kv], sigma-permuted within each 32-kv block).
// 128x128 tile, BK=64, 3-bit XOR chunk swizzle. Grid (512,1,3) with XCD
// swizzle: xcd=wg&7 owns A-row stripe [xcd*8, xcd*8+8) x all 8 cols.
// ---------------------------------------------------------------------------
__global__ __launch_bounds__(256, 2)
void gemm_qkv(const ushort_t* __restrict__ Qb, const ushort_t* __restrict__ Kb,
              const ushort_t* __restrict__ Wqb, const ushort_t* __restrict__ Wkb,
              const ushort_t* __restrict__ Wvb,
              const float* __restrict__ bq, const float* __restrict__ bk,
              const float* __restrict__ bv,
              ushort_t* __restrict__ Qp, ushort_t* __restrict__ Kp,
              ushort_t* __restrict__ Vt)
{
  const int Kd = 1024, Nn = 1024;
  const int z = blockIdx.z;
  const ushort_t* Ab = (z == 0) ? Qb : Kb;
  const ushort_t* Bw = (z == 0) ? Wqb : (z == 1) ? Wkb : Wvb;
  const float* bias  = (z == 0) ? bq : (z == 1) ? bk : bv;

  __shared__ __align__(16) ushort_t As[128][64];
  __shared__ __align__(16) ushort_t Bs[128][64];
  const int tid = threadIdx.x;
  const int lane = tid & 63, wave = tid >> 6;
  const int wm = (wave >> 1) * 64, wn = (wave & 1) * 64;
  const int rq = lane & 15, kg = lane >> 4;

  // XCD swizzle: each XCD gets a contiguous 8-row-tile A stripe (2 MB in L2)
  const int wg = blockIdx.x, xcd = wg & 7, slot = wg >> 3;   // slot 0..63
  const int by = xcd * 8 + (slot >> 3);                      // 0..63
  const int bx = slot & 7;                                   // 0..7
  const int row0 = by * 128, col0 = bx * 128;

  const int st_sub = lane >> 3;                 // row within 8-row group
  const int st_cs  = (lane & 7) ^ st_sub;       // swizzled source 16B chunk

  floatx4 acc[4][4];
#pragma unroll
  for (int i = 0; i < 4; ++i)
#pragma unroll
    for (int j = 0; j < 4; ++j) acc[i][j] = (floatx4){0.f, 0.f, 0.f, 0.f};

  for (int k0 = 0; k0 < Kd; k0 += 64) {
    __syncthreads();
#pragma unroll
    for (int r = 0; r < 4; ++r) {
      int i = wave * 4 + r;                     // 0..15, 8 rows each
      int row = i * 8 + st_sub;
      gld_lds16(Ab + (size_t)(row0 + row) * Kd + k0 + st_cs * 8, (ushort_t*)As + i * 512);
      gld_lds16(Bw + (size_t)(col0 + row) * Kd + k0 + st_cs * 8, (ushort_t*)Bs + i * 512);
    }
    __syncthreads();
#pragma unroll
    for (int kq = 0; kq < 2; ++kq) {
      bf16x8 af[4], bfr[4];
#pragma unroll
      for (int mi = 0; mi < 4; ++mi)
        af[mi] = *(const bf16x8*)&As[wm + mi*16 + rq][((kq*4 + kg) ^ (rq & 7)) * 8];
#pragma unroll
      for (int ni = 0; ni < 4; ++ni)
        bfr[ni] = *(const bf16x8*)&Bs[wn + ni*16 + rq][((kq*4 + kg) ^ (rq & 7)) * 8];
#pragma unroll
      for (int mi = 0; mi < 4; ++mi)
#pragma unroll
        for (int ni = 0; ni < 4; ++ni)
          acc[mi][ni] = mfma16(af[mi], bfr[ni], acc[mi][ni]);
    }
  }

  float bv4[4];
#pragma unroll
  for (int ni = 0; ni < 4; ++ni) bv4[ni] = bias[col0 + wn + ni*16 + rq];

  if (z < 2) {
    ushort_t* Cb = (z == 0) ? Qp : Kp;
#pragma unroll
    for (int mi = 0; mi < 4; ++mi)
#pragma unroll
      for (int ni = 0; ni < 4; ++ni)
#pragma unroll
        for (int rr = 0; rr < 4; ++rr) {
          int row = row0 + wm + mi*16 + kg*4 + rr;
          int col = col0 + wn + ni*16 + rq;
          Cb[(size_t)row * Nn + col] = f2bf(acc[mi][ni][rr] + bv4[ni]);
        }
  } else {
    // sigma layout: kv = base32 + [hi kg1 kg0 r1 r0] stored at
    // position base32 + [kg1 kg0 hi r1 r0]  (hi = mi&1)
#pragma unroll
    for (int mi = 0; mi < 4; ++mi)
#pragma unroll
      for (int ni = 0; ni < 4; ++ni) {
        int col = col0 + wn + ni*16 + rq;       // dv
        int base32 = row0 + wm + (mi >> 1) * 32;
        int p = kg * 8 + (mi & 1) * 4;          // r 0..3 contiguous
        us4 o = { f2bf(acc[mi][ni][0] + bv4[ni]), f2bf(acc[mi][ni][1] + bv4[ni]),
                  f2bf(acc[mi][ni][2] + bv4[ni]), f2bf(acc[mi][ni][3] + bv4[ni]) };
        *(us4*)(Vt + (size_t)col * 8192 + base32 + p) = o;
      }
  }
}

// ---------------------------------------------------------------------------
// Output GEMM: out = bf2f(Ob) + relu(Ob*Wo^T + bo), f32 out. BK=64.
// Grid (512) with the same XCD swizzle as gemm_qkv.
// ---------------------------------------------------------------------------
__global__ __launch_bounds__(256, 2)
void gemm_out(const ushort_t* __restrict__ Ob, const ushort_t* __restrict__ Bw,
              const float* __restrict__ bias, float* __restrict__ Out)
{
  const int Kd = 1024, Nn = 1024;
  __shared__ __align__(16) ushort_t As[128][64];
  __shared__ __align__(16) ushort_t Bs[128][64];
  const int tid = threadIdx.x;
  const int lane = tid & 63, wave = tid >> 6;
  const int wm = (wave >> 1) * 64, wn = (wave & 1) * 64;
  const int rq = lane & 15, kg = lane >> 4;

  const int wg = blockIdx.x, xcd = wg & 7, slot = wg >> 3;
  const int by = xcd * 8 + (slot >> 3);
  const int bx = slot & 7;
  const int row0 = by * 128, col0 = bx * 128;

  const int st_sub = lane >> 3;
  const int st_cs  = (lane & 7) ^ st_sub;

  floatx4 acc[4][4];
#pragma unroll
  for (int i = 0; i < 4; ++i)
#pragma unroll
    for (int j = 0; j < 4; ++j) acc[i][j] = (floatx4){0.f, 0.f, 0.f, 0.f};

  for (int k0 = 0; k0 < Kd; k0 += 64) {
    __syncthreads();
#pragma unroll
    for (int r = 0; r < 4; ++r) {
      int i = wave * 4 + r;
      int row = i * 8 + st_sub;
      gld_lds16(Ob + (size_t)(row0 + row) * Kd + k0 + st_cs * 8, (ushort_t*)As + i * 512);
      gld_lds16(Bw + (size_t)(col0 + row) * Kd + k0 + st_cs * 8, (ushort_t*)Bs + i * 512);
    }
    __syncthreads();
#pragma unroll
    for (int kq = 0; kq < 2; ++kq) {
      bf16x8 af[4], bfr[4];
#pragma unroll
      for (int mi = 0; mi < 4; ++mi)
        af[mi] = *(const bf16x8*)&As[wm + mi*16 + rq][((kq*4 + kg) ^ (rq & 7)) * 8];
#pragma unroll
      for (int ni = 0; ni < 4; ++ni)
        bfr[ni] = *(const bf16x8*)&Bs[wn + ni*16 + rq][((kq*4 + kg) ^ (rq & 7)) * 8];
#pragma unroll
      for (int mi = 0; mi < 4; ++mi)
#pragma unroll
        for (int ni = 0; ni < 4; ++ni)
          acc[mi][ni] = mfma16(af[mi], bfr[ni], acc[mi][ni]);
    }
  }

  float bv4[4];
#pragma unroll
  for (int ni = 0; ni < 4; ++ni) bv4[ni] = bias[col0 + wn + ni*16 + rq];
#pragma unroll
  for (int mi = 0; mi < 4; ++mi)
#pragma unroll
    for (int ni = 0; ni < 4; ++ni)
#pragma unroll
      for (int rr = 0; rr < 4; ++rr) {
        int row = row0 + wm + mi*16 + kg*4 + rr;
        int col = col0 + wn + ni*16 + rq;
        size_t idx = (size_t)row * Nn + col;
        float pre = acc[mi][ni][rr] + bv4[ni];
        Out[idx] = bf2f(Ob[idx]) + (pre > 0.f ? pre : 0.f);
      }
}

// ---------------------------------------------------------------------------
// Flash attention (no-max softmax). BQ=128, BKV=128, d=64, all bf16.
// Wave w owns q rows [w*32, w*32+32); S^T = K*Q^T over the full 128-kv tile,
// softmax + P-pack in registers, PV with P as in-register A-operand (sigma
// V^T). Double-buffered staging, ONE barrier per K-tile.
// Grid (1024) with XCD swizzle: xcd=wg&7 owns 8 bh x 16 qt contiguous, so
// each bh's K/V panels (512 KB) stay resident in that XCD's L2.
// LDS: 2x(Ks 16K + Vs 16K) = 64 KB -> 2 blocks/CU.
// ---------------------------------------------------------------------------
__global__ __launch_bounds__(256, 2)
void attn_kernel(const ushort_t* __restrict__ Qp,
                 const ushort_t* __restrict__ Kp,
                 const ushort_t* __restrict__ Vt,
                 ushort_t* __restrict__ Ob)
{
  const float sc2 = 0.045084439f;  // (1/32) * log2(e)
  const int wg = blockIdx.x, xcd = wg & 7, slot = wg >> 3;   // slot 0..127
  const int bh = xcd * 8 + (slot >> 4);                      // 0..63
  const int qt = slot & 15;                                  // 0..15
  const int b = bh >> 4, h = bh & 15;
  const int q0 = qt * 128;

  __shared__ __align__(16) ushort_t Ks[2][8192];  // K[128][64] per buf
  __shared__ __align__(16) ushort_t Vs[2][8192];  // V^T[64][128] sigma, per buf

  const int tid = threadIdx.x, lane = tid & 63, wq = tid >> 6;  // wq: q-quarter
  const int rq = lane & 15, kg = lane >> 4;

  const size_t qkbase = (size_t)(b * 2048) * 1024 + h * 64;

  // per-lane staging geometry (shared by Q/K and V paths)
  const int sg_sub = lane >> 3;               // row within 8-row group
  const int sg_csk = (lane & 7) ^ sg_sub;     // swizzled 16B chunk (64-col row)

  // stage Q tile (128x64) into Ks[1]
#pragma unroll
  for (int r = 0; r < 4; ++r) {
    int i = wq * 4 + r;
    int row = i * 8 + sg_sub;
    gld_lds16(Qp + qkbase + (size_t)(q0 + row) * 1024 + sg_csk * 8, &Ks[1][i * 512]);
  }
  __syncthreads();

  auto stage = [&](int kt, int bufi) {
    const int kv0 = kt * 128;
#pragma unroll
    for (int r = 0; r < 4; ++r) {
      int i = wq * 4 + r;
      int rowk = i * 8 + sg_sub;
      gld_lds16(Kp + qkbase + (size_t)(kv0 + rowk) * 1024 + sg_csk * 8,
                &Ks[bufi][i * 512]);
      int dv = i * 4 + (lane >> 4);
      int csv = (lane & 15) ^ (dv & 7);
      gld_lds16(Vt + (size_t)(h * 64 + dv) * 8192 + b * 2048 + kv0 + csv * 8,
                &Vs[bufi][i * 512]);
    }
  };
  stage(0, 0);

  // preload Q B-frags scaled by sc2 from Ks[1]: aq[ni][kq], q = wq*32+ni*16+rq
  bf16x8 aq[2][2];
#pragma unroll
  for (int ni = 0; ni < 2; ++ni)
#pragma unroll
    for (int kq = 0; kq < 2; ++kq) {
      int row = wq * 32 + ni * 16 + rq;
      int ch = (kq * 4 + kg) ^ (rq & 7);
      bf16x8 t = *(const bf16x8*)&Ks[1][row * 64 + ch * 8];
#pragma unroll
      for (int e = 0; e < 8; ++e)
        t[e] = (short)f2bf(bf2f((ushort_t)t[e]) * sc2);
      aq[ni][kq] = t;
    }

  // ones B-operand for the l row-sum MFMA (permutation-invariant)
  bf16x8 ones;
#pragma unroll
  for (int e = 0; e < 8; ++e) ones[e] = (short)0x3F80;

  const floatx4 zf = (floatx4){0.f, 0.f, 0.f, 0.f};  // loop-invariant zero C

  floatx4 oacc[2][4];
  floatx4 lacc[2];
#pragma unroll
  for (int nb = 0; nb < 2; ++nb) {
    lacc[nb] = (floatx4){0.f,0.f,0.f,0.f};
#pragma unroll
    for (int dvb = 0; dvb < 4; ++dvb) oacc[nb][dvb] = (floatx4){0.f,0.f,0.f,0.f};
  }

  __syncthreads();   // tile 0 landed; all waves done reading Q from Ks[1]

  int cur = 0;
#pragma unroll 2
  for (int kt = 0; kt < 16; ++kt) {
    // issue next tile's stage into the other buffer (overlaps compute below)
    if (kt < 15) stage(kt + 1, cur ^ 1);

    // S^T = K * Q^T  (mi = kv block 0..7, ni = q block 0..1)
    floatx4 s[8][2];
    __builtin_amdgcn_s_setprio(1);
    {
      bf16x8 ak[8];
#pragma unroll
      for (int mi = 0; mi < 8; ++mi)
        ak[mi] = *(const bf16x8*)&Ks[cur][(mi * 16 + rq) * 64 + ((kg ^ (rq & 7)) * 8)];
#pragma unroll
      for (int mi = 0; mi < 8; ++mi)
#pragma unroll
        for (int ni = 0; ni < 2; ++ni)
          s[mi][ni] = mfma16(ak[mi], aq[ni][0], zf);      // zero-C, no v_movs
#pragma unroll
      for (int mi = 0; mi < 8; ++mi)
        ak[mi] = *(const bf16x8*)&Ks[cur][(mi * 16 + rq) * 64 + (((4 + kg) ^ (rq & 7)) * 8)];
#pragma unroll
      for (int mi = 0; mi < 8; ++mi)
#pragma unroll
        for (int ni = 0; ni < 2; ++ni)
          s[mi][ni] = mfma16(ak[mi], aq[ni][1], s[mi][ni]);
    }
    __builtin_amdgcn_s_setprio(0);

    // exp chunk 0 (mi 0,1); remaining chunks overlap PV MFMAs below
#pragma unroll
    for (int mi = 0; mi < 2; ++mi)
#pragma unroll
      for (int ni = 0; ni < 2; ++ni)
#pragma unroll
        for (int rr = 0; rr < 4; ++rr)
          s[mi][ni][rr] = __builtin_amdgcn_exp2f(s[mi][ni][rr]);

    // O += P V ; l += P 1 : per kv-32 chunk c: pack -> MFMA -> exp(next chunk)
#pragma unroll
    for (int c = 0; c < 4; ++c) {
      bf16x8 vf[4];
#pragma unroll
      for (int dvb = 0; dvb < 4; ++dvb) {
        int dv = dvb * 16 + rq;
        int ch = (c * 4 + kg) ^ (rq & 7);
        vf[dvb] = *(const bf16x8*)&Vs[cur][dv * 128 + ch * 8];
      }
      union { unsigned u[4]; bf16x8 v; } pa0, pa1;
      pa0.u[0] = pk2c(s[2*c  ][0][0], s[2*c  ][0][1]);
      pa0.u[1] = pk2c(s[2*c  ][0][2], s[2*c  ][0][3]);
      pa0.u[2] = pk2c(s[2*c+1][0][0], s[2*c+1][0][1]);
      pa0.u[3] = pk2c(s[2*c+1][0][2], s[2*c+1][0][3]);
      pa1.u[0] = pk2c(s[2*c  ][1][0], s[2*c  ][1][1]);
      pa1.u[1] = pk2c(s[2*c  ][1][2], s[2*c  ][1][3]);
      pa1.u[2] = pk2c(s[2*c+1][1][0], s[2*c+1][1][1]);
      pa1.u[3] = pk2c(s[2*c+1][1][2], s[2*c+1][1][3]);
      __builtin_amdgcn_s_setprio(1);
#pragma unroll
      for (int dvb = 0; dvb < 4; ++dvb) {
        oacc[0][dvb] = mfma16(pa0.v, vf[dvb], oacc[0][dvb]);
        oacc[1][dvb] = mfma16(pa1.v, vf[dvb], oacc[1][dvb]);
      }
      lacc[0] = mfma16(pa0.v, ones, lacc[0]);
      lacc[1] = mfma16(pa1.v, ones, lacc[1]);
      __builtin_amdgcn_s_setprio(0);
      if (c < 3) {   // exp of next chunk issues while PV(c) MFMAs execute
#pragma unroll
        for (int mi = 2*c + 2; mi < 2*c + 4; ++mi)
#pragma unroll
          for (int ni = 0; ni < 2; ++ni)
#pragma unroll
            for (int rr = 0; rr < 4; ++rr)
              s[mi][ni][rr] = __builtin_amdgcn_exp2f(s[mi][ni][rr]);
      }
    }

    __syncthreads();   // next tile landed; all waves done with buf[cur]
    cur ^= 1;
  }

  // epilogue: Oh = Qh + O/l ; l is in-lane at exactly the row we store
#pragma unroll
  for (int nb = 0; nb < 2; ++nb)
#pragma unroll
    for (int rr = 0; rr < 4; ++rr) {
      int row = wq * 32 + nb * 16 + kg * 4 + rr;
      float linv = 1.0f / lacc[nb][rr];
#pragma unroll
      for (int dvb = 0; dvb < 4; ++dvb) {
        int col = dvb * 16 + rq;
        size_t idx = qkbase + (size_t)(q0 + row) * 1024 + col;
        Ob[idx] = f2bf(oacc[nb][dvb][rr] * linv + bf2f(Qp[idx]));
      }
    }
}

// ---------------------------------------------------------------------------
extern "C" void kernel_launch(void* const* d_in, const int* in_sizes, int n_in,
                              void* d_out, int out_size, void* d_ws, size_t ws_size,
                              hipStream_t stream)
{
  const float* Q  = (const float*)d_in[0];
  const float* K  = (const float*)d_in[1];
  const float* Wq = (const float*)d_in[2];
  const float* bq = (const float*)d_in[3];
  const float* Wk = (const float*)d_in[4];
  const float* bk = (const float*)d_in[5];
  const float* Wv = (const float*)d_in[6];
  const float* bv = (const float*)d_in[7];
  const float* Wo = (const float*)d_in[8];
  const float* bo = (const float*)d_in[9];
  float* Out = (float*)d_out;

  ushort_t* ws = (ushort_t*)d_ws;
  const size_t E = (size_t)8192 * 1024;
  const size_t WSZ = (size_t)1024 * 1024;
  ushort_t* Qb  = ws;            // aliased by Ob after attention
  ushort_t* Kb  = ws + E;
  ushort_t* Qp  = ws + 2*E;
  ushort_t* Kp  = ws + 3*E;
  ushort_t* Vt  = ws + 4*E;      // bf16 V^T [1024][8192], sigma kv layout
  ushort_t* Wqb = ws + 5*E;
  ushort_t* Wkb = ws + 5*E + WSZ;
  ushort_t* Wvb = ws + 5*E + 2*WSZ;
  ushort_t* Wob = ws + 5*E + 3*WSZ;
  ushort_t* Ob  = Qb;

  cvt6<<<dim3(4096, 1, 6), 256, 0, stream>>>(Q, K, Wq, Wk, Wv, Wo,
                                             Qb, Kb, Wqb, Wkb, Wvb, Wob);

  dim3 blk(256);
  gemm_qkv<<<dim3(512, 1, 3), blk, 0, stream>>>(Qb, Kb, Wqb, Wkb, Wvb,
                                                bq, bk, bv, Qp, Kp, Vt);
  attn_kernel<<<dim3(1024), blk, 0, stream>>>(Qp, Kp, Vt, Ob);
  gemm_out<<<dim3(512), blk, 0, stream>>>(Ob, Wob, bo, Out);
}